// Round 9
// baseline (7431.313 us; speedup 1.0000x reference)
//
#include <hip/hip_runtime.h>
#include <hip/hip_bf16.h>

namespace {

constexpr int BB = 16;
constexpr int NN = 4096;
constexpr int MM = 1024;

__device__ __forceinline__ float actf(float x, int act) {
    if (act == 1) return fmaxf(x, 0.f);
    if (act == 2) return x >= 0.f ? x : 0.2f * x;
    return x;
}

// ---------------------------------------------------------------------------
// Pointwise-conv GEMM: Y[b][o][l] = sum_c W1[o][c]*X1[b][c][l]
//                                  + sum_c W2[o][c]*X2[b][c][l]  (optional)
//                                  + bias[o]                      (optional)
// Tile: 64 (o) x 128 (l), K-tile 16, 256 threads, 4x8 micro-tile. (unchanged)
// ---------------------------------------------------------------------------
__global__ __launch_bounds__(256)
void conv_gemm(const float* __restrict__ X1, int C1, long x1_bs,
               const float* __restrict__ W1,
               const float* __restrict__ X2, int C2, long x2_bs,
               const float* __restrict__ W2,
               const float* __restrict__ bias,
               float* __restrict__ Y, long y_bs, int L)
{
    __shared__ float Wt[64][17];
    __shared__ float Xt[16][128];
    const int t  = threadIdx.x;
    const int b  = blockIdx.z;
    const int o0 = blockIdx.y * 64;
    const int l0 = blockIdx.x * 128;
    const int ty = t >> 4, tx = t & 15;

    float acc[4][8];
#pragma unroll
    for (int i = 0; i < 4; ++i)
#pragma unroll
        for (int j = 0; j < 8; ++j) acc[i][j] = 0.f;

    for (int pass = 0; pass < 2; ++pass) {
        const float* X = pass ? X2 : X1;
        const float* W = pass ? W2 : W1;
        const int    C = pass ? C2 : C1;
        const long xbs = pass ? x2_bs : x1_bs;
        if (C <= 0 || X == nullptr) continue;
        for (int c0 = 0; c0 < C; c0 += 16) {
            __syncthreads();
#pragma unroll
            for (int i = 0; i < 4; ++i) {
                int flat = i * 256 + t;
                int oo = flat >> 4, kk = flat & 15;
                Wt[oo][kk] = (c0 + kk < C) ? W[(long)(o0 + oo) * C + c0 + kk] : 0.f;
            }
#pragma unroll
            for (int i = 0; i < 2; ++i) {
                int f4 = i * 256 + t;
                int kk = f4 >> 5, c4 = f4 & 31;
                float4 xv = make_float4(0.f, 0.f, 0.f, 0.f);
                if (c0 + kk < C)
                    xv = *reinterpret_cast<const float4*>(
                        X + (long)b * xbs + (long)(c0 + kk) * L + l0 + c4 * 4);
                *reinterpret_cast<float4*>(&Xt[kk][c4 * 4]) = xv;
            }
            __syncthreads();
#pragma unroll
            for (int kk = 0; kk < 16; ++kk) {
                float wv[4];
#pragma unroll
                for (int i = 0; i < 4; ++i) wv[i] = Wt[ty * 4 + i][kk];
                float4 xa = *reinterpret_cast<const float4*>(&Xt[kk][tx * 8]);
                float4 xb = *reinterpret_cast<const float4*>(&Xt[kk][tx * 8 + 4]);
                float xv[8] = {xa.x, xa.y, xa.z, xa.w, xb.x, xb.y, xb.z, xb.w};
#pragma unroll
                for (int i = 0; i < 4; ++i)
#pragma unroll
                    for (int j = 0; j < 8; ++j) acc[i][j] += wv[i] * xv[j];
            }
        }
    }

#pragma unroll
    for (int i = 0; i < 4; ++i) {
        const int oo = o0 + ty * 4 + i;
        const float bv = bias ? bias[oo] : 0.f;
        float* yp = Y + (long)b * y_bs + (long)oo * L + l0 + tx * 8;
        float4 v0 = make_float4(acc[i][0] + bv, acc[i][1] + bv, acc[i][2] + bv, acc[i][3] + bv);
        float4 v1 = make_float4(acc[i][4] + bv, acc[i][5] + bv, acc[i][6] + bv, acc[i][7] + bv);
        *reinterpret_cast<float4*>(yp)     = v0;
        *reinterpret_cast<float4*>(yp + 4) = v1;
    }
}

// ---------------------------------------------------------------------------
// GroupNorm stats (unchanged)
// ---------------------------------------------------------------------------
__global__ __launch_bounds__(256)
void gn_stats(const float* __restrict__ Y, long y_bs, int cpg, int L, int G,
              float* __restrict__ stats)
{
    const int bg = blockIdx.x;
    const int b = bg / G, g = bg - b * G;
    const float* p = Y + (long)b * y_bs + (long)g * cpg * L;
    const long cnt = (long)cpg * L;
    float s = 0.f, ss = 0.f;
    for (long i = (long)threadIdx.x * 4; i < cnt; i += 256 * 4) {
        float4 v = *reinterpret_cast<const float4*>(p + i);
        s  += v.x + v.y + v.z + v.w;
        ss += v.x * v.x + v.y * v.y + v.z * v.z + v.w * v.w;
    }
    __shared__ float rs[256], rss[256];
    rs[threadIdx.x] = s; rss[threadIdx.x] = ss;
    __syncthreads();
    for (int st = 128; st > 0; st >>= 1) {
        if (threadIdx.x < st) {
            rs[threadIdx.x]  += rs[threadIdx.x + st];
            rss[threadIdx.x] += rss[threadIdx.x + st];
        }
        __syncthreads();
    }
    if (threadIdx.x == 0) {
        float mu  = rs[0] / (float)cnt;
        float var = rss[0] / (float)cnt - mu * mu;
        stats[bg * 2]     = mu;
        stats[bg * 2 + 1] = rsqrtf(var + 1e-5f);
    }
}

// ---------------------------------------------------------------------------
// GroupNorm apply (+activation, +optional residual add) (unchanged)
// ---------------------------------------------------------------------------
__global__ __launch_bounds__(256)
void gn_apply(const float* __restrict__ src, long s_bs,
              float* __restrict__ dst, long d_bs,
              const float* __restrict__ res, long r_bs,
              const float* __restrict__ w, const float* __restrict__ bb,
              const float* __restrict__ stats,
              int C, int cpg, int L, int act)
{
    const long total4 = (long)BB * C * L / 4;
    const int G = C / cpg;
    for (long i4 = (long)blockIdx.x * 256 + threadIdx.x; i4 < total4;
         i4 += (long)gridDim.x * 256) {
        long flat = i4 * 4;
        int b = (int)(flat / ((long)C * L));
        long rem = flat - (long)b * C * L;
        int c = (int)(rem / L);
        long li = rem - (long)c * L;
        int sidx = (b * G + c / cpg) * 2;
        float mu = stats[sidx], rsig = stats[sidx + 1];
        float sc = rsig * w[c];
        float sh = bb[c] - mu * sc;
        float4 vv = *reinterpret_cast<const float4*>(src + (long)b * s_bs + (long)c * L + li);
        float4 ov;
        ov.x = actf(vv.x * sc + sh, act);
        ov.y = actf(vv.y * sc + sh, act);
        ov.z = actf(vv.z * sc + sh, act);
        ov.w = actf(vv.w * sc + sh, act);
        if (res) {
            float4 rv = *reinterpret_cast<const float4*>(res + (long)b * r_bs + (long)c * L + li);
            ov.x += rv.x; ov.y += rv.y; ov.z += rv.z; ov.w += rv.w;
        }
        *reinterpret_cast<float4*>(dst + (long)b * d_bs + (long)c * L + li) = ov;
    }
}

// ---------------------------------------------------------------------------
// Fused attention block (unchanged from round 8).
// Block = 16 query rows (RB), 256 threads: r = t&15 (row), g = t>>4 (group).
// PHASE 0: column partial sums csp.  PHASE 1: PV with pre-scaled v', u = q-acc.
// ---------------------------------------------------------------------------
constexpr int RB   = 16;
constexpr int PSTR = 1028;   // multiple of 4 -> float4-aligned rows

template<int DOPV>
__global__ __launch_bounds__(256)
void attn_block(const float* __restrict__ qg, const float* __restrict__ kg,
                const float* __restrict__ vg,
                float* __restrict__ csp,   // phase 0 output
                float* __restrict__ u)     // phase 1 output
{
    __shared__ float T[64 * 68];       // k-tile [d][mm] (S phase) / v-tile [mm][d] (PV)
    __shared__ float Ps[RB * PSTR];    // S -> e -> P rows
    __shared__ float qs[64 * RB];      // q [d][r]
    __shared__ float red[RB * 17];
    __shared__ float mxs[RB], rins[RB];

    const int t  = threadIdx.x;
    const int b  = blockIdx.y;
    const int n0 = blockIdx.x * RB;
    const int r  = t & 15;
    const int g  = t >> 4;

    // stage q[d][r]
    for (int i = 0; i < 4; ++i) {
        int flat = i * 256 + t;              // d*16 + rr
        int d = flat >> 4, rr = flat & 15;
        qs[flat] = qg[(long)b * 64 * NN + (long)d * NN + n0 + rr];
    }

    // ---- S[r][m] for all 16 m-tiles ----
    for (int mt = 0; mt < MM / 64; ++mt) {
        __syncthreads();                     // qs ready / T reusable
        for (int i = 0; i < 16; ++i) {
            int flat = i * 256 + t;          // d*64 + mm
            int d = flat >> 6, mm = flat & 63;
            T[flat] = kg[(long)b * 64 * MM + (long)d * MM + mt * 64 + mm];
        }
        __syncthreads();
        float s0 = 0.f, s1 = 0.f, s2 = 0.f, s3 = 0.f;
#pragma unroll 8
        for (int d = 0; d < 64; ++d) {
            float qv  = qs[d * 16 + r];
            float4 kv = *reinterpret_cast<const float4*>(&T[d * 64 + g * 4]);
            s0 += qv * kv.x; s1 += qv * kv.y; s2 += qv * kv.z; s3 += qv * kv.w;
        }
        *reinterpret_cast<float4*>(&Ps[r * PSTR + mt * 64 + g * 4]) =
            make_float4(s0, s1, s2, s3);
    }
    __syncthreads();

    // ---- row max (16 partials per row, LDS tree) ----
    {
        float mx = -3.0e38f;
        for (int m = g; m < MM; m += 16) mx = fmaxf(mx, Ps[r * PSTR + m]);
        red[r * 17 + g] = mx;
    }
    __syncthreads();
    if (t < RB) {
        float mx = red[t * 17];
        for (int j = 1; j < 16; ++j) mx = fmaxf(mx, red[t * 17 + j]);
        mxs[t] = mx;
    }
    __syncthreads();

    // ---- exp in place + row sum ----
    {
        const float mx = mxs[r];
        float es = 0.f;
        for (int m = g; m < MM; m += 16) {
            float e = __expf(Ps[r * PSTR + m] - mx);
            Ps[r * PSTR + m] = e;
            es += e;
        }
        red[r * 17 + g] = es;
    }
    __syncthreads();
    if (t < RB) {
        float es = 0.f;
        for (int j = 0; j < 16; ++j) es += red[t * 17 + j];
        rins[t] = 1.0f / es;
    }
    __syncthreads();

    if (!DOPV) {
        // column partial sums over this block's 16 rows
        for (int m = t; m < MM; m += 256) {
            float cs = 0.f;
#pragma unroll
            for (int rr = 0; rr < RB; ++rr) cs += Ps[rr * PSTR + m] * rins[rr];
            csp[((long)b * (NN / RB) + blockIdx.x) * MM + m] = cs;
        }
        return;
    }

    // ---- P = e * rinv (each thread scales its own slice of row r) ----
    {
        const float inv = rins[r];
        for (int m = g; m < MM; m += 16) Ps[r * PSTR + m] *= inv;
    }

    // ---- PV: acc(r, d=g*4+i) = sum_m P[r][m] * v'[d][m] ----
    float a0 = 0.f, a1 = 0.f, a2 = 0.f, a3 = 0.f;
    for (int mt = 0; mt < MM / 64; ++mt) {
        __syncthreads();                     // P-scale done / T reusable
        for (int i = 0; i < 16; ++i) {
            int flat = i * 256 + t;          // d*64 + mm
            int d = flat >> 6, mm = flat & 63;
            T[mm * 68 + d] = vg[(long)b * 64 * MM + (long)d * MM + mt * 64 + mm];
        }
        __syncthreads();
#pragma unroll 8
        for (int mm = 0; mm < 64; ++mm) {
            float p   = Ps[r * PSTR + mt * 64 + mm];
            float4 v4 = *reinterpret_cast<const float4*>(&T[mm * 68 + g * 4]);
            a0 += p * v4.x; a1 += p * v4.y; a2 += p * v4.z; a3 += p * v4.w;
        }
    }

    // u[d][n] = q[d][n] - acc,  d = g*4+i, n = n0+r
    const long ub = (long)b * 64 * NN + n0 + r;
    u[ub + (long)(g * 4 + 0) * NN] = qs[(g * 4 + 0) * 16 + r] - a0;
    u[ub + (long)(g * 4 + 1) * NN] = qs[(g * 4 + 1) * 16 + r] - a1;
    u[ub + (long)(g * 4 + 2) * NN] = qs[(g * 4 + 2) * 16 + r] - a2;
    u[ub + (long)(g * 4 + 3) * NN] = qs[(g * 4 + 3) * 16 + r] - a3;
}

__global__ __launch_bounds__(256)
void colsum_reduce(const float* __restrict__ csp, float* __restrict__ cs, int NT)
{
    int idx = blockIdx.x * 256 + threadIdx.x;   // over B*M
    int b = idx / MM, m = idx - b * MM;
    const float* p = csp + (long)b * NT * MM + m;
    float s = 0.f;
    for (int i = 0; i < NT; ++i) s += p[(long)i * MM];
    cs[idx] = s;
}

__global__ __launch_bounds__(256)
void vscale(float* __restrict__ v, const float* __restrict__ cs)
{
    long i4 = (long)blockIdx.x * 256 + threadIdx.x;
    long flat = i4 * 4;                          // index into [B][64][M]
    int b = (int)(flat / (64L * MM));
    int m = (int)(flat % MM);
    float4 vv = *reinterpret_cast<float4*>(v + flat);
    float4 cv = *reinterpret_cast<const float4*>(cs + (long)b * MM + m);
    vv.x /= (1e-9f + cv.x);
    vv.y /= (1e-9f + cv.y);
    vv.z /= (1e-9f + cv.z);
    vv.w /= (1e-9f + cv.w);
    *reinterpret_cast<float4*>(v + flat) = vv;
}

// ---------------------------------------------------------------------------
// Final GN4 + relu + transpose [B][128][N] -> [B][N][128]  (unchanged)
// ---------------------------------------------------------------------------
__global__ __launch_bounds__(256)
void gn_out_transpose(const float* __restrict__ s2,
                      const float* __restrict__ w, const float* __restrict__ bb,
                      const float* __restrict__ stats,
                      float* __restrict__ out)
{
    __shared__ float ls[128 * 65];
    const int t = threadIdx.x;
    const int b = blockIdx.y;
    const int n0 = blockIdx.x * 64;
#pragma unroll
    for (int i = 0; i < 8; ++i) {
        int f4 = i * 256 + t;
        int o = f4 >> 4, c4 = f4 & 15;
        float4 vv = *reinterpret_cast<const float4*>(
            s2 + (long)b * 128 * NN + (long)o * NN + n0 + c4 * 4);
        int sidx = (b * 4 + (o >> 5)) * 2;
        float mu = stats[sidx], rsig = stats[sidx + 1];
        float sc = rsig * w[o], sh = bb[o] - mu * sc;
        ls[o * 65 + c4 * 4 + 0] = fmaxf(vv.x * sc + sh, 0.f);
        ls[o * 65 + c4 * 4 + 1] = fmaxf(vv.y * sc + sh, 0.f);
        ls[o * 65 + c4 * 4 + 2] = fmaxf(vv.z * sc + sh, 0.f);
        ls[o * 65 + c4 * 4 + 3] = fmaxf(vv.w * sc + sh, 0.f);
    }
    __syncthreads();
#pragma unroll
    for (int i = 0; i < 8; ++i) {
        int f4 = i * 256 + t;
        int nn = f4 >> 5, o4 = f4 & 31;
        float4 ov;
        ov.x = ls[(o4 * 4 + 0) * 65 + nn];
        ov.y = ls[(o4 * 4 + 1) * 65 + nn];
        ov.z = ls[(o4 * 4 + 2) * 65 + nn];
        ov.w = ls[(o4 * 4 + 3) * 65 + nn];
        *reinterpret_cast<float4*>(out + (long)b * NN * 128 + (long)(n0 + nn) * 128 + o4 * 4) = ov;
    }
}

} // namespace

extern "C" void kernel_launch(void* const* d_in, const int* in_sizes, int n_in,
                              void* d_out, int out_size, void* d_ws, size_t ws_size,
                              hipStream_t stream)
{
    (void)in_sizes; (void)n_in; (void)out_size; (void)ws_size;

    const float* x         = (const float*)d_in[0];
    const float* x_global  = (const float*)d_in[1];
    const float* xyz       = (const float*)d_in[2];
    const float* xyz_g     = (const float*)d_in[3];
    const float* conv1_w   = (const float*)d_in[4];
    const float* gn1_w     = (const float*)d_in[5];
    const float* gn1_b     = (const float*)d_in[6];
    const float* conv2_w   = (const float*)d_in[7];
    const float* gn2_w     = (const float*)d_in[8];
    const float* gn2_b     = (const float*)d_in[9];
    const float* sa_qk_w   = (const float*)d_in[10];
    const float* sa_v_w    = (const float*)d_in[11];
    const float* sa_v_b    = (const float*)d_in[12];
    const float* sa_t_w    = (const float*)d_in[13];
    const float* sa_t_b    = (const float*)d_in[14];
    const float* sa_gn_w   = (const float*)d_in[15];
    const float* sa_gn_b   = (const float*)d_in[16];
    const float* sa_pos_w  = (const float*)d_in[17];
    const float* sa_posG_w = (const float*)d_in[18];
    const float* fuse_w    = (const float*)d_in[19];
    const float* fuse_gn_w = (const float*)d_in[20];
    const float* fuse_gn_b = (const float*)d_in[21];
    const float* convs1_w  = (const float*)d_in[22];
    const float* convs1_b  = (const float*)d_in[23];
    const float* gns1_w    = (const float*)d_in[24];
    const float* gns1_b    = (const float*)d_in[25];
    const float* convs2_w  = (const float*)d_in[26];
    const float* convs2_b  = (const float*)d_in[27];
    const float* gns2_w    = (const float*)d_in[28];
    const float* gns2_b    = (const float*)d_in[29];

    // ---- workspace layout (float offsets); peak 180.4 MB ----
    // CRITICAL FIX vs round 8: p_st moved to the TAIL of the workspace.
    // Previously it sat inside s1's alias region [0, 33.5M): gn_stats(s1)
    // wrote its 256 stat floats INTO live s1 data -> scattered ~O(1) output
    // errors (absmax 0.91/1.31 in rounds 8/7, shifting as p_st moved).
    constexpr long SZ_BN  = (long)BB * 64 * NN;        // 4,194,304
    constexpr long SZ_BM  = (long)BB * 64 * MM;        // 1,048,576
    constexpr long SZ_CSP = (long)BB * (NN / RB) * MM; // 4,194,304

    float* ws = (float*)d_ws;
    long o = 0;
    float* p_h   = ws + o; o += SZ_BN;               // [B][64][N]  (t-buffer too)
    float* p_hg  = ws + o; o += SZ_BM;               // [B][64][M]
    float* p_q   = ws + o; o += SZ_BN;               // [B][64][N]
    float* p_k   = ws + o; o += SZ_BM;               // [B][64][M]
    float* p_v   = ws + o; o += SZ_BM;               // [B][64][M]
    float* p_u   = ws + o; o += SZ_BN;               // [B][64][N]
    float* p_csp = ws + o; o += SZ_CSP;              // [B][N/16][M]
    float* p_cs  = ws + o; o += (long)BB * MM;       // [B][M]
    float* p_xc  = ws + o; o += (long)BB * 256 * NN; // [B][256][N] 64MB
    float* p_xf  = ws + o; o += (long)BB * 128 * NN; // [B][128][N] 32MB (also s2)
    float* p_st  = ws + o; o += 4096;                // GN stats scratch (TAIL —
                                                     // disjoint from s1 AND s2/xf)
    // s1 [B][512][N] aliases ws[0 .. 33,554,432): SA scratch + csp + cs + xc head,
    // all dead post-fuse; p_xf starts at 36,700,160 -> disjoint from s1.
    float* p_s1  = ws;
    float* p_s2  = p_xf;

    // h = relu(GN16(conv1(x)))
    conv_gemm<<<dim3(NN / 128, 1, BB), 256, 0, stream>>>(
        x, 6, 6L * NN, conv1_w, nullptr, 0, 0, nullptr, nullptr, p_h, 64L * NN, NN);
    gn_stats<<<BB * 16, 256, 0, stream>>>(p_h, 64L * NN, 4, NN, 16, p_st);
    gn_apply<<<2048, 256, 0, stream>>>(p_h, 64L * NN, p_h, 64L * NN, nullptr, 0,
                                       gn1_w, gn1_b, p_st, 64, 4, NN, 1);
    // hg = relu(GN16(conv2(x_global)))
    conv_gemm<<<dim3(MM / 128, 1, BB), 256, 0, stream>>>(
        x_global, 32, 32L * MM, conv2_w, nullptr, 0, 0, nullptr, nullptr, p_hg, 64L * MM, MM);
    gn_stats<<<BB * 16, 256, 0, stream>>>(p_hg, 64L * MM, 4, MM, 16, p_st);
    gn_apply<<<2048, 256, 0, stream>>>(p_hg, 64L * MM, p_hg, 64L * MM, nullptr, 0,
                                       gn2_w, gn2_b, p_st, 64, 4, MM, 1);

    const float* cur = p_h;
    long cur_bs = 64L * NN;
    for (int i = 0; i < 4; ++i) {
        // q = qk_w*cur + pos_w*xyz            -> [B][64][N]
        conv_gemm<<<dim3(NN / 128, 1, BB), 256, 0, stream>>>(
            cur, 64, cur_bs, sa_qk_w + i * 4096,
            xyz, 3, 3L * NN, sa_pos_w + i * 192, nullptr, p_q, 64L * NN, NN);
        // k = qk_w*hg + posG_w*xyz_g          -> [B][64][M]
        conv_gemm<<<dim3(MM / 128, 1, BB), 256, 0, stream>>>(
            p_hg, 64, 64L * MM, sa_qk_w + i * 4096,
            xyz_g, 3, 3L * MM, sa_posG_w + i * 192, nullptr, p_k, 64L * MM, MM);
        // v = v_w*hg + posG_w*xyz_g + v_b     -> [B][64][M]
        conv_gemm<<<dim3(MM / 128, 1, BB), 256, 0, stream>>>(
            p_hg, 64, 64L * MM, sa_v_w + i * 4096,
            xyz_g, 3, 3L * MM, sa_posG_w + i * 192, sa_v_b + i * 64, p_v, 64L * MM, MM);
        // phase 0: softmax stats + column partials
        attn_block<0><<<dim3(NN / RB, BB), 256, 0, stream>>>(p_q, p_k, p_v, p_csp, nullptr);
        colsum_reduce<<<BB * MM / 256, 256, 0, stream>>>(p_csp, p_cs, NN / RB);
        vscale<<<BB * 64 * MM / 1024, 256, 0, stream>>>(p_v, p_cs);
        // phase 1: u = q - P*v'  (S+softmax recomputed identically in-block)
        attn_block<1><<<dim3(NN / RB, BB), 256, 0, stream>>>(p_q, p_k, p_v, nullptr, p_u);
        // t = t_w*u + t_b
        conv_gemm<<<dim3(NN / 128, 1, BB), 256, 0, stream>>>(
            p_u, 64, 64L * NN, sa_t_w + i * 4096,
            nullptr, 0, 0, nullptr, sa_t_b + i * 64, p_h, 64L * NN, NN);
        // out_i = q + relu(GN4(t))  -> xc slice i
        gn_stats<<<BB * 4, 256, 0, stream>>>(p_h, 64L * NN, 16, NN, 4, p_st);
        gn_apply<<<2048, 256, 0, stream>>>(p_h, 64L * NN,
                                           p_xc + (long)i * 64 * NN, 256L * NN,
                                           p_q, 64L * NN,
                                           sa_gn_w + i * 64, sa_gn_b + i * 64, p_st,
                                           64, 16, NN, 1);
        cur = p_xc + (long)i * 64 * NN;
        cur_bs = 256L * NN;
    }

    // xf = leaky(GN16(fuse_w * xc))
    conv_gemm<<<dim3(NN / 128, 2, BB), 256, 0, stream>>>(
        p_xc, 256, 256L * NN, fuse_w, nullptr, 0, 0, nullptr, nullptr, p_xf, 128L * NN, NN);
    gn_stats<<<BB * 16, 256, 0, stream>>>(p_xf, 128L * NN, 8, NN, 16, p_st);
    gn_apply<<<2048, 256, 0, stream>>>(p_xf, 128L * NN, p_xf, 128L * NN, nullptr, 0,
                                       fuse_gn_w, fuse_gn_b, p_st, 128, 8, NN, 2);
    // s1 = relu(GN8(convs1_w * xf + b))   (s1 aliases dead SA scratch + xc head)
    conv_gemm<<<dim3(NN / 128, 8, BB), 256, 0, stream>>>(
        p_xf, 128, 128L * NN, convs1_w, nullptr, 0, 0, nullptr, convs1_b, p_s1, 512L * NN, NN);
    gn_stats<<<BB * 8, 256, 0, stream>>>(p_s1, 512L * NN, 64, NN, 8, p_st);
    gn_apply<<<2048, 256, 0, stream>>>(p_s1, 512L * NN, p_s1, 512L * NN, nullptr, 0,
                                       gns1_w, gns1_b, p_st, 512, 64, NN, 1);
    // s2 = GN4(convs2_w * s1 + b), relu fused into transpose (s2 aliases xf)
    conv_gemm<<<dim3(NN / 128, 2, BB), 256, 0, stream>>>(
        p_s1, 512, 512L * NN, convs2_w, nullptr, 0, 0, nullptr, convs2_b, p_s2, 128L * NN, NN);
    gn_stats<<<BB * 4, 256, 0, stream>>>(p_s2, 128L * NN, 32, NN, 4, p_st);
    gn_out_transpose<<<dim3(NN / 64, BB), 256, 0, stream>>>(
        p_s2, gns2_w, gns2_b, p_st, (float*)d_out);
}

// Round 10
// 3804.057 us; speedup vs baseline: 1.9535x; 1.9535x over previous
//
#include <hip/hip_runtime.h>
#include <hip/hip_bf16.h>

namespace {

constexpr int BB = 16;
constexpr int NN = 4096;
constexpr int MM = 1024;

__device__ __forceinline__ float actf(float x, int act) {
    if (act == 1) return fmaxf(x, 0.f);
    if (act == 2) return x >= 0.f ? x : 0.2f * x;
    return x;
}

// ---------------------------------------------------------------------------
// Pointwise-conv GEMM (unchanged — control)
// ---------------------------------------------------------------------------
__global__ __launch_bounds__(256)
void conv_gemm(const float* __restrict__ X1, int C1, long x1_bs,
               const float* __restrict__ W1,
               const float* __restrict__ X2, int C2, long x2_bs,
               const float* __restrict__ W2,
               const float* __restrict__ bias,
               float* __restrict__ Y, long y_bs, int L)
{
    __shared__ float Wt[64][17];
    __shared__ float Xt[16][128];
    const int t  = threadIdx.x;
    const int b  = blockIdx.z;
    const int o0 = blockIdx.y * 64;
    const int l0 = blockIdx.x * 128;
    const int ty = t >> 4, tx = t & 15;

    float acc[4][8];
#pragma unroll
    for (int i = 0; i < 4; ++i)
#pragma unroll
        for (int j = 0; j < 8; ++j) acc[i][j] = 0.f;

    for (int pass = 0; pass < 2; ++pass) {
        const float* X = pass ? X2 : X1;
        const float* W = pass ? W2 : W1;
        const int    C = pass ? C2 : C1;
        const long xbs = pass ? x2_bs : x1_bs;
        if (C <= 0 || X == nullptr) continue;
        for (int c0 = 0; c0 < C; c0 += 16) {
            __syncthreads();
#pragma unroll
            for (int i = 0; i < 4; ++i) {
                int flat = i * 256 + t;
                int oo = flat >> 4, kk = flat & 15;
                Wt[oo][kk] = (c0 + kk < C) ? W[(long)(o0 + oo) * C + c0 + kk] : 0.f;
            }
#pragma unroll
            for (int i = 0; i < 2; ++i) {
                int f4 = i * 256 + t;
                int kk = f4 >> 5, c4 = f4 & 31;
                float4 xv = make_float4(0.f, 0.f, 0.f, 0.f);
                if (c0 + kk < C)
                    xv = *reinterpret_cast<const float4*>(
                        X + (long)b * xbs + (long)(c0 + kk) * L + l0 + c4 * 4);
                *reinterpret_cast<float4*>(&Xt[kk][c4 * 4]) = xv;
            }
            __syncthreads();
#pragma unroll
            for (int kk = 0; kk < 16; ++kk) {
                float wv[4];
#pragma unroll
                for (int i = 0; i < 4; ++i) wv[i] = Wt[ty * 4 + i][kk];
                float4 xa = *reinterpret_cast<const float4*>(&Xt[kk][tx * 8]);
                float4 xb = *reinterpret_cast<const float4*>(&Xt[kk][tx * 8 + 4]);
                float xv[8] = {xa.x, xa.y, xa.z, xa.w, xb.x, xb.y, xb.z, xb.w};
#pragma unroll
                for (int i = 0; i < 4; ++i)
#pragma unroll
                    for (int j = 0; j < 8; ++j) acc[i][j] += wv[i] * xv[j];
            }
        }
    }

#pragma unroll
    for (int i = 0; i < 4; ++i) {
        const int oo = o0 + ty * 4 + i;
        const float bv = bias ? bias[oo] : 0.f;
        float* yp = Y + (long)b * y_bs + (long)oo * L + l0 + tx * 8;
        float4 v0 = make_float4(acc[i][0] + bv, acc[i][1] + bv, acc[i][2] + bv, acc[i][3] + bv);
        float4 v1 = make_float4(acc[i][4] + bv, acc[i][5] + bv, acc[i][6] + bv, acc[i][7] + bv);
        *reinterpret_cast<float4*>(yp)     = v0;
        *reinterpret_cast<float4*>(yp + 4) = v1;
    }
}

// ---------------------------------------------------------------------------
// GroupNorm stats (unchanged)
// ---------------------------------------------------------------------------
__global__ __launch_bounds__(256)
void gn_stats(const float* __restrict__ Y, long y_bs, int cpg, int L, int G,
              float* __restrict__ stats)
{
    const int bg = blockIdx.x;
    const int b = bg / G, g = bg - b * G;
    const float* p = Y + (long)b * y_bs + (long)g * cpg * L;
    const long cnt = (long)cpg * L;
    float s = 0.f, ss = 0.f;
    for (long i = (long)threadIdx.x * 4; i < cnt; i += 256 * 4) {
        float4 v = *reinterpret_cast<const float4*>(p + i);
        s  += v.x + v.y + v.z + v.w;
        ss += v.x * v.x + v.y * v.y + v.z * v.z + v.w * v.w;
    }
    __shared__ float rs[256], rss[256];
    rs[threadIdx.x] = s; rss[threadIdx.x] = ss;
    __syncthreads();
    for (int st = 128; st > 0; st >>= 1) {
        if (threadIdx.x < st) {
            rs[threadIdx.x]  += rs[threadIdx.x + st];
            rss[threadIdx.x] += rss[threadIdx.x + st];
        }
        __syncthreads();
    }
    if (threadIdx.x == 0) {
        float mu  = rs[0] / (float)cnt;
        float var = rss[0] / (float)cnt - mu * mu;
        stats[bg * 2]     = mu;
        stats[bg * 2 + 1] = rsqrtf(var + 1e-5f);
    }
}

// ---------------------------------------------------------------------------
// GroupNorm apply (unchanged)
// ---------------------------------------------------------------------------
__global__ __launch_bounds__(256)
void gn_apply(const float* __restrict__ src, long s_bs,
              float* __restrict__ dst, long d_bs,
              const float* __restrict__ res, long r_bs,
              const float* __restrict__ w, const float* __restrict__ bb,
              const float* __restrict__ stats,
              int C, int cpg, int L, int act)
{
    const long total4 = (long)BB * C * L / 4;
    const int G = C / cpg;
    for (long i4 = (long)blockIdx.x * 256 + threadIdx.x; i4 < total4;
         i4 += (long)gridDim.x * 256) {
        long flat = i4 * 4;
        int b = (int)(flat / ((long)C * L));
        long rem = flat - (long)b * C * L;
        int c = (int)(rem / L);
        long li = rem - (long)c * L;
        int sidx = (b * G + c / cpg) * 2;
        float mu = stats[sidx], rsig = stats[sidx + 1];
        float sc = rsig * w[c];
        float sh = bb[c] - mu * sc;
        float4 vv = *reinterpret_cast<const float4*>(src + (long)b * s_bs + (long)c * L + li);
        float4 ov;
        ov.x = actf(vv.x * sc + sh, act);
        ov.y = actf(vv.y * sc + sh, act);
        ov.z = actf(vv.z * sc + sh, act);
        ov.w = actf(vv.w * sc + sh, act);
        if (res) {
            float4 rv = *reinterpret_cast<const float4*>(res + (long)b * r_bs + (long)c * L + li);
            ov.x += rv.x; ov.y += rv.y; ov.z += rv.z; ov.w += rv.w;
        }
        *reinterpret_cast<float4*>(dst + (long)b * d_bs + (long)c * L + li) = ov;
    }
}

// ---------------------------------------------------------------------------
// Attention, restructured for occupancy + register blocking.
// Both phases: block = 16 q-rows (RB) x 1024 m, 256 threads.
// S compute: thread (nr = t>>6, mc = t&63) owns a 4n x 4m micro-tile of the
// current 256-wide m-tile; K staged in 8-deep d-chunks with register prefetch.
// 16 FMA per 2 ds_read_b128 -> VALU-bound. LDS < 80KB -> 2 blocks/CU.
// Phase 0 (attn_stats2): exact row softmax stats (same algorithm as round 8)
//   -> rowmax/rowinv global + per-block column partials csp.
// Phase 1 (attn_pv3): recompute S, P = exp(S-mx)*rinv in registers, PV with
//   pre-scaled v', u = q - acc.
// ---------------------------------------------------------------------------
constexpr int RB  = 16;
constexpr int SST = 1028;   // S row stride: %4==0 (f4-aligned), %32==4 (2-way banks)

__global__ __launch_bounds__(256)
void attn_stats2(const float* __restrict__ qg, const float* __restrict__ kg,
                 float* __restrict__ rowmax, float* __restrict__ rowinv,
                 float* __restrict__ csp)
{
    __shared__ float Sx[RB * SST];       // 65,792 B
    __shared__ float qs[64 * 16];        //  4,096 B   [d][n]
    __shared__ float kb[8 * 260];        //  8,320 B   [dd][m] chunk
    __shared__ float red[RB * 17];
    __shared__ float mxs[RB], rins[RB];

    const int t  = threadIdx.x;
    const int b  = blockIdx.y;
    const int n0 = blockIdx.x * RB;
    const int nr = t >> 6;               // wave id -> rows 4nr..4nr+3
    const int mc = t & 63;               // cols 4mc..4mc+3 within 256-wide m-tile
    const int srow = t >> 5;             // staging row 0..7
    const int scol = (t & 31) * 8;       // staging col

    // stage q[d][n]
    for (int i = 0; i < 4; ++i) {
        int f = i * 256 + t;
        int d = f >> 4, nn = f & 15;
        qs[d * 16 + nn] = qg[(long)b * 64 * NN + (long)d * NN + n0 + nn];
    }

    const float* kbase = kg + (long)b * 64 * MM;

    for (int mt = 0; mt < 4; ++mt) {
        const int m0 = mt * 256;
        float acc[4][4];
#pragma unroll
        for (int j = 0; j < 4; ++j)
#pragma unroll
            for (int i = 0; i < 4; ++i) acc[j][i] = 0.f;

        float4 pa = *reinterpret_cast<const float4*>(kbase + (long)srow * MM + m0 + scol);
        float4 pb = *reinterpret_cast<const float4*>(kbase + (long)srow * MM + m0 + scol + 4);
        for (int c = 0; c < 8; ++c) {
            __syncthreads();             // kb free (and qs visible on c==0,mt==0)
            *reinterpret_cast<float4*>(&kb[srow * 260 + scol])     = pa;
            *reinterpret_cast<float4*>(&kb[srow * 260 + scol + 4]) = pb;
            __syncthreads();
            if (c < 7) {
                pa = *reinterpret_cast<const float4*>(
                    kbase + (long)((c + 1) * 8 + srow) * MM + m0 + scol);
                pb = *reinterpret_cast<const float4*>(
                    kbase + (long)((c + 1) * 8 + srow) * MM + m0 + scol + 4);
            }
#pragma unroll
            for (int dd = 0; dd < 8; ++dd) {
                float4 qv = *reinterpret_cast<const float4*>(&qs[(c * 8 + dd) * 16 + nr * 4]);
                float4 kv = *reinterpret_cast<const float4*>(&kb[dd * 260 + mc * 4]);
                acc[0][0] += qv.x * kv.x; acc[0][1] += qv.x * kv.y; acc[0][2] += qv.x * kv.z; acc[0][3] += qv.x * kv.w;
                acc[1][0] += qv.y * kv.x; acc[1][1] += qv.y * kv.y; acc[1][2] += qv.y * kv.z; acc[1][3] += qv.y * kv.w;
                acc[2][0] += qv.z * kv.x; acc[2][1] += qv.z * kv.y; acc[2][2] += qv.z * kv.z; acc[2][3] += qv.z * kv.w;
                acc[3][0] += qv.w * kv.x; acc[3][1] += qv.w * kv.y; acc[3][2] += qv.w * kv.z; acc[3][3] += qv.w * kv.w;
            }
        }
#pragma unroll
        for (int j = 0; j < 4; ++j)
            *reinterpret_cast<float4*>(&Sx[(nr * 4 + j) * SST + m0 + mc * 4]) =
                make_float4(acc[j][0], acc[j][1], acc[j][2], acc[j][3]);
    }
    __syncthreads();

    // ---- row softmax stats (same algorithm as round 8: r = t&15, g = t>>4) ----
    const int r = t & 15, g = t >> 4;
    {
        float mx = -3.0e38f;
        for (int m = g; m < MM; m += 16) mx = fmaxf(mx, Sx[r * SST + m]);
        red[r * 17 + g] = mx;
    }
    __syncthreads();
    if (t < RB) {
        float mx = red[t * 17];
        for (int j = 1; j < 16; ++j) mx = fmaxf(mx, red[t * 17 + j]);
        mxs[t] = mx;
        rowmax[(long)b * NN + n0 + t] = mx;
    }
    __syncthreads();
    {
        const float mx = mxs[r];
        float es = 0.f;
        for (int m = g; m < MM; m += 16) {
            float e = __expf(Sx[r * SST + m] - mx);
            Sx[r * SST + m] = e;
            es += e;
        }
        red[r * 17 + g] = es;
    }
    __syncthreads();
    if (t < RB) {
        float es = 0.f;
        for (int j = 0; j < 16; ++j) es += red[t * 17 + j];
        float inv = 1.0f / es;
        rins[t] = inv;
        rowinv[(long)b * NN + n0 + t] = inv;
    }
    __syncthreads();

    // ---- column partial sums over this block's 16 rows ----
    for (int m = t; m < MM; m += 256) {
        float cs = 0.f;
#pragma unroll
        for (int rr = 0; rr < RB; ++rr) cs += Sx[rr * SST + m] * rins[rr];
        csp[((long)b * (NN / RB) + blockIdx.x) * MM + m] = cs;
    }
}

__global__ __launch_bounds__(256)
void attn_pv3(const float* __restrict__ qg, const float* __restrict__ kg,
              const float* __restrict__ vg,
              const float* __restrict__ rowmax, const float* __restrict__ rowinv,
              float* __restrict__ u)
{
    __shared__ float Sx[RB * SST];       // 65,792 B (holds P after conversion)
    __shared__ float qs[64 * 16];        //  4,096 B
    __shared__ float ubuf[2176];         //  8,704 B: kb [8][260] then vb [32][68]

    const int t  = threadIdx.x;
    const int b  = blockIdx.y;
    const int n0 = blockIdx.x * RB;
    const int nr = t >> 6;
    const int mc = t & 63;
    const int srow = t >> 5;
    const int scol = (t & 31) * 8;

    for (int i = 0; i < 4; ++i) {
        int f = i * 256 + t;
        int d = f >> 4, nn = f & 15;
        qs[d * 16 + nn] = qg[(long)b * 64 * NN + (long)d * NN + n0 + nn];
    }

    // per-wave row stats (rows 4nr..4nr+3), from phase 0
    float mx[4], ri[4];
#pragma unroll
    for (int j = 0; j < 4; ++j) {
        mx[j] = rowmax[(long)b * NN + n0 + nr * 4 + j];
        ri[j] = rowinv[(long)b * NN + n0 + nr * 4 + j];
    }

    const float* kbase = kg + (long)b * 64 * MM;

    for (int mt = 0; mt < 4; ++mt) {
        const int m0 = mt * 256;
        float acc[4][4];
#pragma unroll
        for (int j = 0; j < 4; ++j)
#pragma unroll
            for (int i = 0; i < 4; ++i) acc[j][i] = 0.f;

        float4 pa = *reinterpret_cast<const float4*>(kbase + (long)srow * MM + m0 + scol);
        float4 pb = *reinterpret_cast<const float4*>(kbase + (long)srow * MM + m0 + scol + 4);
        for (int c = 0; c < 8; ++c) {
            __syncthreads();
            *reinterpret_cast<float4*>(&ubuf[srow * 260 + scol])     = pa;
            *reinterpret_cast<float4*>(&ubuf[srow * 260 + scol + 4]) = pb;
            __syncthreads();
            if (c < 7) {
                pa = *reinterpret_cast<const float4*>(
                    kbase + (long)((c + 1) * 8 + srow) * MM + m0 + scol);
                pb = *reinterpret_cast<const float4*>(
                    kbase + (long)((c + 1) * 8 + srow) * MM + m0 + scol + 4);
            }
#pragma unroll
            for (int dd = 0; dd < 8; ++dd) {
                float4 qv = *reinterpret_cast<const float4*>(&qs[(c * 8 + dd) * 16 + nr * 4]);
                float4 kv = *reinterpret_cast<const float4*>(&ubuf[dd * 260 + mc * 4]);
                acc[0][0] += qv.x * kv.x; acc[0][1] += qv.x * kv.y; acc[0][2] += qv.x * kv.z; acc[0][3] += qv.x * kv.w;
                acc[1][0] += qv.y * kv.x; acc[1][1] += qv.y * kv.y; acc[1][2] += qv.y * kv.z; acc[1][3] += qv.y * kv.w;
                acc[2][0] += qv.z * kv.x; acc[2][1] += qv.z * kv.y; acc[2][2] += qv.z * kv.z; acc[2][3] += qv.z * kv.w;
                acc[3][0] += qv.w * kv.x; acc[3][1] += qv.w * kv.y; acc[3][2] += qv.w * kv.z; acc[3][3] += qv.w * kv.w;
            }
        }
        // P = exp(S - mx) * rinv, straight to LDS
#pragma unroll
        for (int j = 0; j < 4; ++j)
            *reinterpret_cast<float4*>(&Sx[(nr * 4 + j) * SST + m0 + mc * 4]) =
                make_float4(__expf(acc[j][0] - mx[j]) * ri[j],
                            __expf(acc[j][1] - mx[j]) * ri[j],
                            __expf(acc[j][2] - mx[j]) * ri[j],
                            __expf(acc[j][3] - mx[j]) * ri[j]);
    }

    // ---- PV: acc(r, d=4dg+i) = sum_m P[r][m] * v'[d][m] ----
    const int r  = t & 15;
    const int dg = t >> 4;               // 0..15 -> d = 4dg..4dg+3
    float a0 = 0.f, a1 = 0.f, a2 = 0.f, a3 = 0.f;
    const float* vbase = vg + (long)b * 64 * MM;

    for (int ch = 0; ch < 32; ++ch) {
        const int m0c = ch * 32;
        __syncthreads();                 // P ready (ch==0) / vb free
        for (int i = 0; i < 8; ++i) {
            int f = i * 256 + t;         // 2048 = 64d x 32m
            int dd = f >> 5, mm = f & 31;
            ubuf[mm * 68 + dd] = vbase[(long)dd * MM + m0c + mm];
        }
        __syncthreads();
#pragma unroll 8
        for (int mm = 0; mm < 32; ++mm) {
            float p   = Sx[r * SST + m0c + mm];
            float4 vv = *reinterpret_cast<const float4*>(&ubuf[mm * 68 + dg * 4]);
            a0 += p * vv.x; a1 += p * vv.y; a2 += p * vv.z; a3 += p * vv.w;
        }
    }

    const long ub = (long)b * 64 * NN + n0 + r;
    u[ub + (long)(dg * 4 + 0) * NN] = qs[(dg * 4 + 0) * 16 + r] - a0;
    u[ub + (long)(dg * 4 + 1) * NN] = qs[(dg * 4 + 1) * 16 + r] - a1;
    u[ub + (long)(dg * 4 + 2) * NN] = qs[(dg * 4 + 2) * 16 + r] - a2;
    u[ub + (long)(dg * 4 + 3) * NN] = qs[(dg * 4 + 3) * 16 + r] - a3;
}

__global__ __launch_bounds__(256)
void colsum_reduce(const float* __restrict__ csp, float* __restrict__ cs, int NT)
{
    int idx = blockIdx.x * 256 + threadIdx.x;   // over B*M
    int b = idx / MM, m = idx - b * MM;
    const float* p = csp + (long)b * NT * MM + m;
    float s = 0.f;
    for (int i = 0; i < NT; ++i) s += p[(long)i * MM];
    cs[idx] = s;
}

__global__ __launch_bounds__(256)
void vscale(float* __restrict__ v, const float* __restrict__ cs)
{
    long i4 = (long)blockIdx.x * 256 + threadIdx.x;
    long flat = i4 * 4;                          // index into [B][64][M]
    int b = (int)(flat / (64L * MM));
    int m = (int)(flat % MM);
    float4 vv = *reinterpret_cast<float4*>(v + flat);
    float4 cv = *reinterpret_cast<const float4*>(cs + (long)b * MM + m);
    vv.x /= (1e-9f + cv.x);
    vv.y /= (1e-9f + cv.y);
    vv.z /= (1e-9f + cv.z);
    vv.w /= (1e-9f + cv.w);
    *reinterpret_cast<float4*>(v + flat) = vv;
}

// ---------------------------------------------------------------------------
// Final GN4 + relu + transpose (unchanged)
// ---------------------------------------------------------------------------
__global__ __launch_bounds__(256)
void gn_out_transpose(const float* __restrict__ s2,
                      const float* __restrict__ w, const float* __restrict__ bb,
                      const float* __restrict__ stats,
                      float* __restrict__ out)
{
    __shared__ float ls[128 * 65];
    const int t = threadIdx.x;
    const int b = blockIdx.y;
    const int n0 = blockIdx.x * 64;
#pragma unroll
    for (int i = 0; i < 8; ++i) {
        int f4 = i * 256 + t;
        int o = f4 >> 4, c4 = f4 & 15;
        float4 vv = *reinterpret_cast<const float4*>(
            s2 + (long)b * 128 * NN + (long)o * NN + n0 + c4 * 4);
        int sidx = (b * 4 + (o >> 5)) * 2;
        float mu = stats[sidx], rsig = stats[sidx + 1];
        float sc = rsig * w[o], sh = bb[o] - mu * sc;
        ls[o * 65 + c4 * 4 + 0] = fmaxf(vv.x * sc + sh, 0.f);
        ls[o * 65 + c4 * 4 + 1] = fmaxf(vv.y * sc + sh, 0.f);
        ls[o * 65 + c4 * 4 + 2] = fmaxf(vv.z * sc + sh, 0.f);
        ls[o * 65 + c4 * 4 + 3] = fmaxf(vv.w * sc + sh, 0.f);
    }
    __syncthreads();
#pragma unroll
    for (int i = 0; i < 8; ++i) {
        int f4 = i * 256 + t;
        int nn = f4 >> 5, o4 = f4 & 31;
        float4 ov;
        ov.x = ls[(o4 * 4 + 0) * 65 + nn];
        ov.y = ls[(o4 * 4 + 1) * 65 + nn];
        ov.z = ls[(o4 * 4 + 2) * 65 + nn];
        ov.w = ls[(o4 * 4 + 3) * 65 + nn];
        *reinterpret_cast<float4*>(out + (long)b * NN * 128 + (long)(n0 + nn) * 128 + o4 * 4) = ov;
    }
}

} // namespace

extern "C" void kernel_launch(void* const* d_in, const int* in_sizes, int n_in,
                              void* d_out, int out_size, void* d_ws, size_t ws_size,
                              hipStream_t stream)
{
    (void)in_sizes; (void)n_in; (void)out_size; (void)ws_size;

    const float* x         = (const float*)d_in[0];
    const float* x_global  = (const float*)d_in[1];
    const float* xyz       = (const float*)d_in[2];
    const float* xyz_g     = (const float*)d_in[3];
    const float* conv1_w   = (const float*)d_in[4];
    const float* gn1_w     = (const float*)d_in[5];
    const float* gn1_b     = (const float*)d_in[6];
    const float* conv2_w   = (const float*)d_in[7];
    const float* gn2_w     = (const float*)d_in[8];
    const float* gn2_b     = (const float*)d_in[9];
    const float* sa_qk_w   = (const float*)d_in[10];
    const float* sa_v_w    = (const float*)d_in[11];
    const float* sa_v_b    = (const float*)d_in[12];
    const float* sa_t_w    = (const float*)d_in[13];
    const float* sa_t_b    = (const float*)d_in[14];
    const float* sa_gn_w   = (const float*)d_in[15];
    const float* sa_gn_b   = (const float*)d_in[16];
    const float* sa_pos_w  = (const float*)d_in[17];
    const float* sa_posG_w = (const float*)d_in[18];
    const float* fuse_w    = (const float*)d_in[19];
    const float* fuse_gn_w = (const float*)d_in[20];
    const float* fuse_gn_b = (const float*)d_in[21];
    const float* convs1_w  = (const float*)d_in[22];
    const float* convs1_b  = (const float*)d_in[23];
    const float* gns1_w    = (const float*)d_in[24];
    const float* gns1_b    = (const float*)d_in[25];
    const float* convs2_w  = (const float*)d_in[26];
    const float* convs2_b  = (const float*)d_in[27];
    const float* gns2_w    = (const float*)d_in[28];
    const float* gns2_b    = (const float*)d_in[29];

    // ---- workspace layout; peak ~180.9 MB (round-9-proven size class) ----
    // p_st / p_rmx / p_rin live at the TAIL, disjoint from the s1 alias region.
    constexpr long SZ_BN  = (long)BB * 64 * NN;        // 4,194,304
    constexpr long SZ_BM  = (long)BB * 64 * MM;        // 1,048,576
    constexpr long SZ_CSP = (long)BB * (NN / RB) * MM; // 4,194,304

    float* ws = (float*)d_ws;
    long o = 0;
    float* p_h   = ws + o; o += SZ_BN;               // [B][64][N]  (t-buffer too)
    float* p_hg  = ws + o; o += SZ_BM;               // [B][64][M]
    float* p_q   = ws + o; o += SZ_BN;               // [B][64][N]
    float* p_k   = ws + o; o += SZ_BM;               // [B][64][M]
    float* p_v   = ws + o; o += SZ_BM;               // [B][64][M]
    float* p_u   = ws + o; o += SZ_BN;               // [B][64][N]
    float* p_csp = ws + o; o += SZ_CSP;              // [B][N/16][M]
    float* p_cs  = ws + o; o += (long)BB * MM;       // [B][M]
    float* p_xc  = ws + o; o += (long)BB * 256 * NN; // [B][256][N] 64MB
    float* p_xf  = ws + o; o += (long)BB * 128 * NN; // [B][128][N] 32MB (also s2)
    float* p_st  = ws + o; o += 4096;                // GN stats scratch (tail)
    float* p_rmx = ws + o; o += (long)BB * NN;       // [B][N] row max (tail)
    float* p_rin = ws + o; o += (long)BB * NN;       // [B][N] row 1/sum (tail)
    // s1 [B][512][N] aliases ws[0 .. 33,554,432): SA scratch + csp + cs + xc head,
    // all dead post-fuse; p_xf starts at 36,700,160 -> disjoint.
    float* p_s1  = ws;
    float* p_s2  = p_xf;

    // h = relu(GN16(conv1(x)))
    conv_gemm<<<dim3(NN / 128, 1, BB), 256, 0, stream>>>(
        x, 6, 6L * NN, conv1_w, nullptr, 0, 0, nullptr, nullptr, p_h, 64L * NN, NN);
    gn_stats<<<BB * 16, 256, 0, stream>>>(p_h, 64L * NN, 4, NN, 16, p_st);
    gn_apply<<<2048, 256, 0, stream>>>(p_h, 64L * NN, p_h, 64L * NN, nullptr, 0,
                                       gn1_w, gn1_b, p_st, 64, 4, NN, 1);
    // hg = relu(GN16(conv2(x_global)))
    conv_gemm<<<dim3(MM / 128, 1, BB), 256, 0, stream>>>(
        x_global, 32, 32L * MM, conv2_w, nullptr, 0, 0, nullptr, nullptr, p_hg, 64L * MM, MM);
    gn_stats<<<BB * 16, 256, 0, stream>>>(p_hg, 64L * MM, 4, MM, 16, p_st);
    gn_apply<<<2048, 256, 0, stream>>>(p_hg, 64L * MM, p_hg, 64L * MM, nullptr, 0,
                                       gn2_w, gn2_b, p_st, 64, 4, MM, 1);

    const float* cur = p_h;
    long cur_bs = 64L * NN;
    for (int i = 0; i < 4; ++i) {
        // q = qk_w*cur + pos_w*xyz            -> [B][64][N]
        conv_gemm<<<dim3(NN / 128, 1, BB), 256, 0, stream>>>(
            cur, 64, cur_bs, sa_qk_w + i * 4096,
            xyz, 3, 3L * NN, sa_pos_w + i * 192, nullptr, p_q, 64L * NN, NN);
        // k = qk_w*hg + posG_w*xyz_g          -> [B][64][M]
        conv_gemm<<<dim3(MM / 128, 1, BB), 256, 0, stream>>>(
            p_hg, 64, 64L * MM, sa_qk_w + i * 4096,
            xyz_g, 3, 3L * MM, sa_posG_w + i * 192, nullptr, p_k, 64L * MM, MM);
        // v = v_w*hg + posG_w*xyz_g + v_b     -> [B][64][M]
        conv_gemm<<<dim3(MM / 128, 1, BB), 256, 0, stream>>>(
            p_hg, 64, 64L * MM, sa_v_w + i * 4096,
            xyz_g, 3, 3L * MM, sa_posG_w + i * 192, sa_v_b + i * 64, p_v, 64L * MM, MM);
        // phase 0: softmax stats + column partials
        attn_stats2<<<dim3(NN / RB, BB), 256, 0, stream>>>(p_q, p_k, p_rmx, p_rin, p_csp);
        colsum_reduce<<<BB * MM / 256, 256, 0, stream>>>(p_csp, p_cs, NN / RB);
        vscale<<<BB * 64 * MM / 1024, 256, 0, stream>>>(p_v, p_cs);
        // phase 1: u = q - P*v'
        attn_pv3<<<dim3(NN / RB, BB), 256, 0, stream>>>(p_q, p_k, p_v, p_rmx, p_rin, p_u);
        // t = t_w*u + t_b
        conv_gemm<<<dim3(NN / 128, 1, BB), 256, 0, stream>>>(
            p_u, 64, 64L * NN, sa_t_w + i * 4096,
            nullptr, 0, 0, nullptr, sa_t_b + i * 64, p_h, 64L * NN, NN);
        // out_i = q + relu(GN4(t))  -> xc slice i
        gn_stats<<<BB * 4, 256, 0, stream>>>(p_h, 64L * NN, 16, NN, 4, p_st);
        gn_apply<<<2048, 256, 0, stream>>>(p_h, 64L * NN,
                                           p_xc + (long)i * 64 * NN, 256L * NN,
                                           p_q, 64L * NN,
                                           sa_gn_w + i * 64, sa_gn_b + i * 64, p_st,
                                           64, 16, NN, 1);
        cur = p_xc + (long)i * 64 * NN;
        cur_bs = 256L * NN;
    }

    // xf = leaky(GN16(fuse_w * xc))
    conv_gemm<<<dim3(NN / 128, 2, BB), 256, 0, stream>>>(
        p_xc, 256, 256L * NN, fuse_w, nullptr, 0, 0, nullptr, nullptr, p_xf, 128L * NN, NN);
    gn_stats<<<BB * 16, 256, 0, stream>>>(p_xf, 128L * NN, 8, NN, 16, p_st);
    gn_apply<<<2048, 256, 0, stream>>>(p_xf, 128L * NN, p_xf, 128L * NN, nullptr, 0,
                                       fuse_gn_w, fuse_gn_b, p_st, 128, 8, NN, 2);
    // s1 = relu(GN8(convs1_w * xf + b))
    conv_gemm<<<dim3(NN / 128, 8, BB), 256, 0, stream>>>(
        p_xf, 128, 128L * NN, convs1_w, nullptr, 0, 0, nullptr, convs1_b, p_s1, 512L * NN, NN);
    gn_stats<<<BB * 8, 256, 0, stream>>>(p_s1, 512L * NN, 64, NN, 8, p_st);
    gn_apply<<<2048, 256, 0, stream>>>(p_s1, 512L * NN, p_s1, 512L * NN, nullptr, 0,
                                       gns1_w, gns1_b, p_st, 512, 64, NN, 1);
    // s2 = GN4(convs2_w * s1 + b), relu fused into transpose
    conv_gemm<<<dim3(NN / 128, 2, BB), 256, 0, stream>>>(
        p_s1, 512, 512L * NN, convs2_w, nullptr, 0, 0, nullptr, convs2_b, p_s2, 128L * NN, NN);
    gn_stats<<<BB * 4, 256, 0, stream>>>(p_s2, 128L * NN, 32, NN, 4, p_st);
    gn_out_transpose<<<dim3(NN / 64, BB), 256, 0, stream>>>(
        p_s2, gns2_w, gns2_b, p_st, (float*)d_out);
}

// Round 11
// 1996.553 us; speedup vs baseline: 3.7221x; 1.9053x over previous
//
#include <hip/hip_runtime.h>
#include <hip/hip_bf16.h>

namespace {

constexpr int BB = 16;
constexpr int NN = 4096;
constexpr int MM = 1024;

using f32x4  = __attribute__((ext_vector_type(4))) float;
using bf16x8 = __attribute__((ext_vector_type(8))) short;

__device__ __forceinline__ float actf(float x, int act) {
    if (act == 1) return fmaxf(x, 0.f);
    if (act == 2) return x >= 0.f ? x : 0.2f * x;
    return x;
}

__device__ __forceinline__ ushort f2bf(float x) {
    __hip_bfloat16 h = __float2bfloat16(x);
    return *reinterpret_cast<ushort*>(&h);
}

// ---------------------------------------------------------------------------
// Pointwise-conv GEMM (unchanged — control)
// ---------------------------------------------------------------------------
__global__ __launch_bounds__(256)
void conv_gemm(const float* __restrict__ X1, int C1, long x1_bs,
               const float* __restrict__ W1,
               const float* __restrict__ X2, int C2, long x2_bs,
               const float* __restrict__ W2,
               const float* __restrict__ bias,
               float* __restrict__ Y, long y_bs, int L)
{
    __shared__ float Wt[64][17];
    __shared__ float Xt[16][128];
    const int t  = threadIdx.x;
    const int b  = blockIdx.z;
    const int o0 = blockIdx.y * 64;
    const int l0 = blockIdx.x * 128;
    const int ty = t >> 4, tx = t & 15;

    float acc[4][8];
#pragma unroll
    for (int i = 0; i < 4; ++i)
#pragma unroll
        for (int j = 0; j < 8; ++j) acc[i][j] = 0.f;

    for (int pass = 0; pass < 2; ++pass) {
        const float* X = pass ? X2 : X1;
        const float* W = pass ? W2 : W1;
        const int    C = pass ? C2 : C1;
        const long xbs = pass ? x2_bs : x1_bs;
        if (C <= 0 || X == nullptr) continue;
        for (int c0 = 0; c0 < C; c0 += 16) {
            __syncthreads();
#pragma unroll
            for (int i = 0; i < 4; ++i) {
                int flat = i * 256 + t;
                int oo = flat >> 4, kk = flat & 15;
                Wt[oo][kk] = (c0 + kk < C) ? W[(long)(o0 + oo) * C + c0 + kk] : 0.f;
            }
#pragma unroll
            for (int i = 0; i < 2; ++i) {
                int f4 = i * 256 + t;
                int kk = f4 >> 5, c4 = f4 & 31;
                float4 xv = make_float4(0.f, 0.f, 0.f, 0.f);
                if (c0 + kk < C)
                    xv = *reinterpret_cast<const float4*>(
                        X + (long)b * xbs + (long)(c0 + kk) * L + l0 + c4 * 4);
                *reinterpret_cast<float4*>(&Xt[kk][c4 * 4]) = xv;
            }
            __syncthreads();
#pragma unroll
            for (int kk = 0; kk < 16; ++kk) {
                float wv[4];
#pragma unroll
                for (int i = 0; i < 4; ++i) wv[i] = Wt[ty * 4 + i][kk];
                float4 xa = *reinterpret_cast<const float4*>(&Xt[kk][tx * 8]);
                float4 xb = *reinterpret_cast<const float4*>(&Xt[kk][tx * 8 + 4]);
                float xv[8] = {xa.x, xa.y, xa.z, xa.w, xb.x, xb.y, xb.z, xb.w};
#pragma unroll
                for (int i = 0; i < 4; ++i)
#pragma unroll
                    for (int j = 0; j < 8; ++j) acc[i][j] += wv[i] * xv[j];
            }
        }
    }

#pragma unroll
    for (int i = 0; i < 4; ++i) {
        const int oo = o0 + ty * 4 + i;
        const float bv = bias ? bias[oo] : 0.f;
        float* yp = Y + (long)b * y_bs + (long)oo * L + l0 + tx * 8;
        float4 v0 = make_float4(acc[i][0] + bv, acc[i][1] + bv, acc[i][2] + bv, acc[i][3] + bv);
        float4 v1 = make_float4(acc[i][4] + bv, acc[i][5] + bv, acc[i][6] + bv, acc[i][7] + bv);
        *reinterpret_cast<float4*>(yp)     = v0;
        *reinterpret_cast<float4*>(yp + 4) = v1;
    }
}

// ---------------------------------------------------------------------------
// GroupNorm stats / apply (unchanged)
// ---------------------------------------------------------------------------
__global__ __launch_bounds__(256)
void gn_stats(const float* __restrict__ Y, long y_bs, int cpg, int L, int G,
              float* __restrict__ stats)
{
    const int bg = blockIdx.x;
    const int b = bg / G, g = bg - b * G;
    const float* p = Y + (long)b * y_bs + (long)g * cpg * L;
    const long cnt = (long)cpg * L;
    float s = 0.f, ss = 0.f;
    for (long i = (long)threadIdx.x * 4; i < cnt; i += 256 * 4) {
        float4 v = *reinterpret_cast<const float4*>(p + i);
        s  += v.x + v.y + v.z + v.w;
        ss += v.x * v.x + v.y * v.y + v.z * v.z + v.w * v.w;
    }
    __shared__ float rs[256], rss[256];
    rs[threadIdx.x] = s; rss[threadIdx.x] = ss;
    __syncthreads();
    for (int st = 128; st > 0; st >>= 1) {
        if (threadIdx.x < st) {
            rs[threadIdx.x]  += rs[threadIdx.x + st];
            rss[threadIdx.x] += rss[threadIdx.x + st];
        }
        __syncthreads();
    }
    if (threadIdx.x == 0) {
        float mu  = rs[0] / (float)cnt;
        float var = rss[0] / (float)cnt - mu * mu;
        stats[bg * 2]     = mu;
        stats[bg * 2 + 1] = rsqrtf(var + 1e-5f);
    }
}

__global__ __launch_bounds__(256)
void gn_apply(const float* __restrict__ src, long s_bs,
              float* __restrict__ dst, long d_bs,
              const float* __restrict__ res, long r_bs,
              const float* __restrict__ w, const float* __restrict__ bb,
              const float* __restrict__ stats,
              int C, int cpg, int L, int act)
{
    const long total4 = (long)BB * C * L / 4;
    const int G = C / cpg;
    for (long i4 = (long)blockIdx.x * 256 + threadIdx.x; i4 < total4;
         i4 += (long)gridDim.x * 256) {
        long flat = i4 * 4;
        int b = (int)(flat / ((long)C * L));
        long rem = flat - (long)b * C * L;
        int c = (int)(rem / L);
        long li = rem - (long)c * L;
        int sidx = (b * G + c / cpg) * 2;
        float mu = stats[sidx], rsig = stats[sidx + 1];
        float sc = rsig * w[c];
        float sh = bb[c] - mu * sc;
        float4 vv = *reinterpret_cast<const float4*>(src + (long)b * s_bs + (long)c * L + li);
        float4 ov;
        ov.x = actf(vv.x * sc + sh, act);
        ov.y = actf(vv.y * sc + sh, act);
        ov.z = actf(vv.z * sc + sh, act);
        ov.w = actf(vv.w * sc + sh, act);
        if (res) {
            float4 rv = *reinterpret_cast<const float4*>(res + (long)b * r_bs + (long)c * L + li);
            ov.x += rv.x; ov.y += rv.y; ov.z += rv.z; ov.w += rv.w;
        }
        *reinterpret_cast<float4*>(dst + (long)b * d_bs + (long)c * L + li) = ov;
    }
}

// ---------------------------------------------------------------------------
// Transpose+convert: in [B][64][L] f32 -> out [B][L][64] bf16
// ---------------------------------------------------------------------------
__global__ __launch_bounds__(256)
void tcvt(const float* __restrict__ in, ushort* __restrict__ out, int L)
{
    __shared__ float ls[64][65];
    const int t = threadIdx.x, b = blockIdx.y;
    const int l0 = blockIdx.x * 64;
#pragma unroll
    for (int i = 0; i < 16; ++i) {
        int f = i * 256 + t;
        int d = f >> 6, l = f & 63;
        ls[d][l] = in[(long)b * 64 * L + (long)d * L + l0 + l];
    }
    __syncthreads();
#pragma unroll
    for (int i = 0; i < 16; ++i) {
        int f = i * 256 + t;
        int l = f >> 6, d = f & 63;
        out[((long)b * L + l0 + l) * 64 + d] = f2bf(ls[d][l]);
    }
}

// ---------------------------------------------------------------------------
// MFMA attention phase 0: S in registers, stats via shuffles.
// Block = 16 q-rows, 4 waves; wave w owns m-strip [w*256, w*256+256).
// qt: [B][N][64] bf16, kt: [B][M][64] bf16.
// Frag layouts (m89-verified): A row=lane&15,k=(lane>>4)*8+j; B col=lane&15,
// k=(lane>>4)*8+j; C/D col=lane&15,row=(lane>>4)*4+reg.
// ---------------------------------------------------------------------------
__global__ __launch_bounds__(256)
void attn_stats_mfma(const ushort* __restrict__ qt, const ushort* __restrict__ kt,
                     float* __restrict__ rowmax, float* __restrict__ rowinv,
                     float* __restrict__ csp)
{
    __shared__ float red[16][5];
    __shared__ float rs_mx[16], rs_inv[16];

    const int t  = threadIdx.x;
    const int b  = blockIdx.y;
    const int n0 = blockIdx.x * 16;
    const int w  = t >> 6;
    const int ln = t & 15;
    const int lq = (t >> 4) & 3;

    const ushort* qtb = qt + ((long)b * NN + n0) * 64;
    const ushort* ktb = kt + (long)b * MM * 64;

    bf16x8 aq[2];
#pragma unroll
    for (int ks = 0; ks < 2; ++ks)
        aq[ks] = *reinterpret_cast<const bf16x8*>(qtb + (long)ln * 64 + ks * 32 + lq * 8);

    f32x4 sc[16];
#pragma unroll
    for (int i = 0; i < 16; ++i) {
        const int m0 = (w * 16 + i) * 16;
        f32x4 acc = {0.f, 0.f, 0.f, 0.f};
#pragma unroll
        for (int ks = 0; ks < 2; ++ks) {
            bf16x8 bk = *reinterpret_cast<const bf16x8*>(
                ktb + (long)(m0 + ln) * 64 + ks * 32 + lq * 8);
            acc = __builtin_amdgcn_mfma_f32_16x16x32_bf16(aq[ks], bk, acc, 0, 0, 0);
        }
        sc[i] = acc;
    }

    // wave-local row max (reduce over ln within each 16-lane group)
    float m4[4];
#pragma unroll
    for (int r = 0; r < 4; ++r) {
        float mx = sc[0][r];
#pragma unroll
        for (int i = 1; i < 16; ++i) mx = fmaxf(mx, sc[i][r]);
#pragma unroll
        for (int off = 1; off <= 8; off <<= 1) mx = fmaxf(mx, __shfl_xor(mx, off, 64));
        m4[r] = mx;
    }
    if (ln == 0)
#pragma unroll
        for (int r = 0; r < 4; ++r) red[lq * 4 + r][w] = m4[r];
    __syncthreads();
    if (t < 16) {
        float mx = fmaxf(fmaxf(red[t][0], red[t][1]), fmaxf(red[t][2], red[t][3]));
        rs_mx[t] = mx;
        rowmax[(long)b * NN + n0 + t] = mx;
    }
    __syncthreads();

    // exp + row sums
    float mxr[4], s4[4];
#pragma unroll
    for (int r = 0; r < 4; ++r) { mxr[r] = rs_mx[lq * 4 + r]; s4[r] = 0.f; }
#pragma unroll
    for (int i = 0; i < 16; ++i)
#pragma unroll
        for (int r = 0; r < 4; ++r) {
            float e = __expf(sc[i][r] - mxr[r]);
            sc[i][r] = e;
            s4[r] += e;
        }
#pragma unroll
    for (int r = 0; r < 4; ++r)
#pragma unroll
        for (int off = 1; off <= 8; off <<= 1) s4[r] += __shfl_xor(s4[r], off, 64);
    if (ln == 0)
#pragma unroll
        for (int r = 0; r < 4; ++r) red[lq * 4 + r][w] = s4[r];
    __syncthreads();
    if (t < 16) {
        float es = red[t][0] + red[t][1] + red[t][2] + red[t][3];
        float inv = 1.0f / es;
        rs_inv[t] = inv;
        rowinv[(long)b * NN + n0 + t] = inv;
    }
    __syncthreads();

    // column partials: lane's column m = (w*16+i)*16 + ln, sum over 16 rows
    float riv[4];
#pragma unroll
    for (int r = 0; r < 4; ++r) riv[r] = rs_inv[lq * 4 + r];
    const long cbase = ((long)b * (NN / 16) + blockIdx.x) * MM;
#pragma unroll
    for (int i = 0; i < 16; ++i) {
        float c = sc[i][0] * riv[0] + sc[i][1] * riv[1] + sc[i][2] * riv[2] + sc[i][3] * riv[3];
        c += __shfl_xor(c, 16, 64);
        c += __shfl_xor(c, 32, 64);
        if (lq == 0) csp[cbase + (w * 16 + i) * 16 + ln] = c;
    }
}

// ---------------------------------------------------------------------------
// MFMA attention phase 1: recompute S (bit-identical), P bf16 -> swizzled LDS,
// PV = V'^T * P^T on MFMA, u = q - acc.
// ---------------------------------------------------------------------------
__global__ __launch_bounds__(256)
void attn_pv_mfma(const ushort* __restrict__ qt, const ushort* __restrict__ kt,
                  const ushort* __restrict__ vb,
                  const float* __restrict__ rowmax, const float* __restrict__ rowinv,
                  const float* __restrict__ qg, float* __restrict__ ug)
{
    __shared__ ushort Pb[16 * 1024];   // 32 KB, XOR-swizzled rows

    const int t  = threadIdx.x;
    const int b  = blockIdx.y;
    const int n0 = blockIdx.x * 16;
    const int w  = t >> 6;
    const int ln = t & 15;
    const int lq = (t >> 4) & 3;

    const ushort* qtb = qt + ((long)b * NN + n0) * 64;
    const ushort* ktb = kt + (long)b * MM * 64;

    float mx[4], ri[4];
#pragma unroll
    for (int r = 0; r < 4; ++r) {
        mx[r] = rowmax[(long)b * NN + n0 + lq * 4 + r];
        ri[r] = rowinv[(long)b * NN + n0 + lq * 4 + r];
    }

    bf16x8 aq[2];
#pragma unroll
    for (int ks = 0; ks < 2; ++ks)
        aq[ks] = *reinterpret_cast<const bf16x8*>(qtb + (long)ln * 64 + ks * 32 + lq * 8);

#pragma unroll
    for (int i = 0; i < 16; ++i) {
        const int m0 = (w * 16 + i) * 16;
        f32x4 acc = {0.f, 0.f, 0.f, 0.f};
#pragma unroll
        for (int ks = 0; ks < 2; ++ks) {
            bf16x8 bk = *reinterpret_cast<const bf16x8*>(
                ktb + (long)(m0 + ln) * 64 + ks * 32 + lq * 8);
            acc = __builtin_amdgcn_mfma_f32_16x16x32_bf16(aq[ks], bk, acc, 0, 0, 0);
        }
#pragma unroll
        for (int r = 0; r < 4; ++r) {
            const int n = lq * 4 + r;
            float p = __expf(acc[r] - mx[r]) * ri[r];
            Pb[n * 1024 + ((m0 + ln) ^ ((n & 7) << 3))] = f2bf(p);
        }
    }
    __syncthreads();

    // PV: wave w owns d-tile d0 = w*16.  D2[d][n] = sum_m V'[d][m] * P[n][m]
    const ushort* vbb = vb + (long)b * 64 * MM;
    const int d0 = w * 16;
    f32x4 acc = {0.f, 0.f, 0.f, 0.f};
#pragma unroll 8
    for (int ks = 0; ks < 32; ++ks) {
        bf16x8 av = *reinterpret_cast<const bf16x8*>(
            vbb + (long)(d0 + ln) * MM + ks * 32 + lq * 8);
        bf16x8 bp = *reinterpret_cast<const bf16x8*>(
            &Pb[ln * 1024 + ((ks * 32 + lq * 8) ^ ((ln & 7) << 3))]);
        acc = __builtin_amdgcn_mfma_f32_16x16x32_bf16(av, bp, acc, 0, 0, 0);
    }

    const long qb = (long)b * 64 * NN;
#pragma unroll
    for (int r = 0; r < 4; ++r) {
        const int dd = d0 + lq * 4 + r;
        const long idx = qb + (long)dd * NN + n0 + ln;
        ug[idx] = qg[idx] - acc[r];
    }
}

__global__ __launch_bounds__(256)
void colsum_reduce(const float* __restrict__ csp, float* __restrict__ cs, int NT)
{
    int idx = blockIdx.x * 256 + threadIdx.x;   // over B*M
    int b = idx / MM, m = idx - b * MM;
    const float* p = csp + (long)b * NT * MM + m;
    float s = 0.f;
    for (int i = 0; i < NT; ++i) s += p[(long)i * MM];
    cs[idx] = s;
}

// v' = v / (1e-9 + colsum), converted to bf16 [B][64][M]
__global__ __launch_bounds__(256)
void vscale_cvt(const float* __restrict__ v, const float* __restrict__ cs,
                ushort* __restrict__ vb)
{
    long i4 = (long)blockIdx.x * 256 + threadIdx.x;
    long flat = i4 * 4;                          // index into [B][64][M]
    int b = (int)(flat / (64L * MM));
    int m = (int)(flat % MM);
    float4 vv = *reinterpret_cast<const float4*>(v + flat);
    float4 cv = *reinterpret_cast<const float4*>(cs + (long)b * MM + m);
    ushort4 o;
    o.x = f2bf(vv.x / (1e-9f + cv.x));
    o.y = f2bf(vv.y / (1e-9f + cv.y));
    o.z = f2bf(vv.z / (1e-9f + cv.z));
    o.w = f2bf(vv.w / (1e-9f + cv.w));
    *reinterpret_cast<ushort4*>(vb + flat) = o;
}

// ---------------------------------------------------------------------------
// Final GN4 + relu + transpose (unchanged)
// ---------------------------------------------------------------------------
__global__ __launch_bounds__(256)
void gn_out_transpose(const float* __restrict__ s2,
                      const float* __restrict__ w, const float* __restrict__ bb,
                      const float* __restrict__ stats,
                      float* __restrict__ out)
{
    __shared__ float ls[128 * 65];
    const int t = threadIdx.x;
    const int b = blockIdx.y;
    const int n0 = blockIdx.x * 64;
#pragma unroll
    for (int i = 0; i < 8; ++i) {
        int f4 = i * 256 + t;
        int o = f4 >> 4, c4 = f4 & 15;
        float4 vv = *reinterpret_cast<const float4*>(
            s2 + (long)b * 128 * NN + (long)o * NN + n0 + c4 * 4);
        int sidx = (b * 4 + (o >> 5)) * 2;
        float mu = stats[sidx], rsig = stats[sidx + 1];
        float sc = rsig * w[o], sh = bb[o] - mu * sc;
        ls[o * 65 + c4 * 4 + 0] = fmaxf(vv.x * sc + sh, 0.f);
        ls[o * 65 + c4 * 4 + 1] = fmaxf(vv.y * sc + sh, 0.f);
        ls[o * 65 + c4 * 4 + 2] = fmaxf(vv.z * sc + sh, 0.f);
        ls[o * 65 + c4 * 4 + 3] = fmaxf(vv.w * sc + sh, 0.f);
    }
    __syncthreads();
#pragma unroll
    for (int i = 0; i < 8; ++i) {
        int f4 = i * 256 + t;
        int nn = f4 >> 5, o4 = f4 & 31;
        float4 ov;
        ov.x = ls[(o4 * 4 + 0) * 65 + nn];
        ov.y = ls[(o4 * 4 + 1) * 65 + nn];
        ov.z = ls[(o4 * 4 + 2) * 65 + nn];
        ov.w = ls[(o4 * 4 + 3) * 65 + nn];
        *reinterpret_cast<float4*>(out + (long)b * NN * 128 + (long)(n0 + nn) * 128 + o4 * 4) = ov;
    }
}

} // namespace

extern "C" void kernel_launch(void* const* d_in, const int* in_sizes, int n_in,
                              void* d_out, int out_size, void* d_ws, size_t ws_size,
                              hipStream_t stream)
{
    (void)in_sizes; (void)n_in; (void)out_size; (void)ws_size;

    const float* x         = (const float*)d_in[0];
    const float* x_global  = (const float*)d_in[1];
    const float* xyz       = (const float*)d_in[2];
    const float* xyz_g     = (const float*)d_in[3];
    const float* conv1_w   = (const float*)d_in[4];
    const float* gn1_w     = (const float*)d_in[5];
    const float* gn1_b     = (const float*)d_in[6];
    const float* conv2_w   = (const float*)d_in[7];
    const float* gn2_w     = (const float*)d_in[8];
    const float* gn2_b     = (const float*)d_in[9];
    const float* sa_qk_w   = (const float*)d_in[10];
    const float* sa_v_w    = (const float*)d_in[11];
    const float* sa_v_b    = (const float*)d_in[12];
    const float* sa_t_w    = (const float*)d_in[13];
    const float* sa_t_b    = (const float*)d_in[14];
    const float* sa_gn_w   = (const float*)d_in[15];
    const float* sa_gn_b   = (const float*)d_in[16];
    const float* sa_pos_w  = (const float*)d_in[17];
    const float* sa_posG_w = (const float*)d_in[18];
    const float* fuse_w    = (const float*)d_in[19];
    const float* fuse_gn_w = (const float*)d_in[20];
    const float* fuse_gn_b = (const float*)d_in[21];
    const float* convs1_w  = (const float*)d_in[22];
    const float* convs1_b  = (const float*)d_in[23];
    const float* gns1_w    = (const float*)d_in[24];
    const float* gns1_b    = (const float*)d_in[25];
    const float* convs2_w  = (const float*)d_in[26];
    const float* convs2_b  = (const float*)d_in[27];
    const float* gns2_w    = (const float*)d_in[28];
    const float* gns2_b    = (const float*)d_in[29];

    // ---- workspace layout; peak ~180.9 MB (round-10-proven) ----
    constexpr long SZ_BN  = (long)BB * 64 * NN;        // 4,194,304
    constexpr long SZ_BM  = (long)BB * 64 * MM;        // 1,048,576
    constexpr long SZ_CSP = (long)BB * (NN / 16) * MM; // 4,194,304

    float* ws = (float*)d_ws;
    long o = 0;
    float* p_h   = ws + o; o += SZ_BN;               // [B][64][N]  (t-buffer too)
    float* p_hg  = ws + o; o += SZ_BM;               // [B][64][M]
    float* p_q   = ws + o; o += SZ_BN;               // [B][64][N]
    float* p_k   = ws + o; o += SZ_BM;               // [B][64][M]
    float* p_v   = ws + o; o += SZ_BM;               // [B][64][M]
    float* p_u   = ws + o; o += SZ_BN;               // [B][64][N]
    float* p_csp = ws + o; o += SZ_CSP;              // [B][N/16][M]
    float* p_cs  = ws + o; o += (long)BB * MM;       // [B][M]
    float* p_xc  = ws + o; o += (long)BB * 256 * NN; // [B][256][N] 64MB
    float* p_xf  = ws + o; o += (long)BB * 128 * NN; // [B][128][N] 32MB (also s2)
    float* p_st  = ws + o; o += 4096;                // GN stats scratch (tail)
    float* p_rmx = ws + o; o += (long)BB * NN;       // [B][N] row max (tail)
    float* p_rin = ws + o; o += (long)BB * NN;       // [B][N] row 1/sum (tail)
    // s1 [B][512][N] aliases ws[0 .. 33,554,432), dead post-fuse; p_xf disjoint.
    float* p_s1  = ws;
    float* p_s2  = p_xf;
    // bf16 buffers alias the (SA-phase-dead) xf region: 12 MB of its 32 MB.
    ushort* p_qt = (ushort*)p_xf;                              // [B][N][64] bf16
    ushort* p_kt = (ushort*)(p_xf + 2097152);                  // [B][M][64] bf16
    ushort* p_vb = (ushort*)(p_xf + 2097152 + 524288);         // [B][64][M] bf16

    // h = relu(GN16(conv1(x)))
    conv_gemm<<<dim3(NN / 128, 1, BB), 256, 0, stream>>>(
        x, 6, 6L * NN, conv1_w, nullptr, 0, 0, nullptr, nullptr, p_h, 64L * NN, NN);
    gn_stats<<<BB * 16, 256, 0, stream>>>(p_h, 64L * NN, 4, NN, 16, p_st);
    gn_apply<<<2048, 256, 0, stream>>>(p_h, 64L * NN, p_h, 64L * NN, nullptr, 0,
                                       gn1_w, gn1_b, p_st, 64, 4, NN, 1);
    // hg = relu(GN16(conv2(x_global)))
    conv_gemm<<<dim3(MM / 128, 1, BB), 256, 0, stream>>>(
        x_global, 32, 32L * MM, conv2_w, nullptr, 0, 0, nullptr, nullptr, p_hg, 64L * MM, MM);
    gn_stats<<<BB * 16, 256, 0, stream>>>(p_hg, 64L * MM, 4, MM, 16, p_st);
    gn_apply<<<2048, 256, 0, stream>>>(p_hg, 64L * MM, p_hg, 64L * MM, nullptr, 0,
                                       gn2_w, gn2_b, p_st, 64, 4, MM, 1);

    const float* cur = p_h;
    long cur_bs = 64L * NN;
    for (int i = 0; i < 4; ++i) {
        // q = qk_w*cur + pos_w*xyz            -> [B][64][N]
        conv_gemm<<<dim3(NN / 128, 1, BB), 256, 0, stream>>>(
            cur, 64, cur_bs, sa_qk_w + i * 4096,
            xyz, 3, 3L * NN, sa_pos_w + i * 192, nullptr, p_q, 64L * NN, NN);
        tcvt<<<dim3(NN / 64, BB), 256, 0, stream>>>(p_q, p_qt, NN);
        // k = qk_w*hg + posG_w*xyz_g          -> [B][64][M]
        conv_gemm<<<dim3(MM / 128, 1, BB), 256, 0, stream>>>(
            p_hg, 64, 64L * MM, sa_qk_w + i * 4096,
            xyz_g, 3, 3L * MM, sa_posG_w + i * 192, nullptr, p_k, 64L * MM, MM);
        tcvt<<<dim3(MM / 64, BB), 256, 0, stream>>>(p_k, p_kt, MM);
        // v = v_w*hg + posG_w*xyz_g + v_b     -> [B][64][M]
        conv_gemm<<<dim3(MM / 128, 1, BB), 256, 0, stream>>>(
            p_hg, 64, 64L * MM, sa_v_w + i * 4096,
            xyz_g, 3, 3L * MM, sa_posG_w + i * 192, sa_v_b + i * 64, p_v, 64L * MM, MM);
        // phase 0: MFMA softmax stats + column partials
        attn_stats_mfma<<<dim3(NN / 16, BB), 256, 0, stream>>>(p_qt, p_kt, p_rmx, p_rin, p_csp);
        colsum_reduce<<<BB * MM / 256, 256, 0, stream>>>(p_csp, p_cs, NN / 16);
        vscale_cvt<<<BB * 64 * MM / 1024, 256, 0, stream>>>(p_v, p_cs, p_vb);
        // phase 1: u = q - P*v'  (S recomputed bit-identically on MFMA)
        attn_pv_mfma<<<dim3(NN / 16, BB), 256, 0, stream>>>(
            p_qt, p_kt, p_vb, p_rmx, p_rin, p_q, p_u);
        // t = t_w*u + t_b
        conv_gemm<<<dim3(NN / 128, 1, BB), 256, 0, stream>>>(
            p_u, 64, 64L * NN, sa_t_w + i * 4096,
            nullptr, 0, 0, nullptr, sa_t_b + i * 64, p_h, 64L * NN, NN);
        // out_i = q + relu(GN4(t))  -> xc slice i
        gn_stats<<<BB * 4, 256, 0, stream>>>(p_h, 64L * NN, 16, NN, 4, p_st);
        gn_apply<<<2048, 256, 0, stream>>>(p_h, 64L * NN,
                                           p_xc + (long)i * 64 * NN, 256L * NN,
                                           p_q, 64L * NN,
                                           sa_gn_w + i * 64, sa_gn_b + i * 64, p_st,
                                           64, 16, NN, 1);
        cur = p_xc + (long)i * 64 * NN;
        cur_bs = 256L * NN;
    }

    // xf = leaky(GN16(fuse_w * xc))
    conv_gemm<<<dim3(NN / 128, 2, BB), 256, 0, stream>>>(
        p_xc, 256, 256L * NN, fuse_w, nullptr, 0, 0, nullptr, nullptr, p_xf, 128L * NN, NN);
    gn_stats<<<BB * 16, 256, 0, stream>>>(p_xf, 128L * NN, 8, NN, 16, p_st);
    gn_apply<<<2048, 256, 0, stream>>>(p_xf, 128L * NN, p_xf, 128L * NN, nullptr, 0,
                                       fuse_gn_w, fuse_gn_b, p_st, 128, 8, NN, 2);
    // s1 = relu(GN8(convs1_w * xf + b))
    conv_gemm<<<dim3(NN / 128, 8, BB), 256, 0, stream>>>(
        p_xf, 128, 128L * NN, convs1_w, nullptr, 0, 0, nullptr, convs1_b, p_s1, 512L * NN, NN);
    gn_stats<<<BB * 8, 256, 0, stream>>>(p_s1, 512L * NN, 64, NN, 8, p_st);
    gn_apply<<<2048, 256, 0, stream>>>(p_s1, 512L * NN, p_s1, 512L * NN, nullptr, 0,
                                       gns1_w, gns1_b, p_st, 512, 64, NN, 1);
    // s2 = GN4(convs2_w * s1 + b), relu fused into transpose
    conv_gemm<<<dim3(NN / 128, 2, BB), 256, 0, stream>>>(
        p_s1, 512, 512L * NN, convs2_w, nullptr, 0, 0, nullptr, convs2_b, p_s2, 128L * NN, NN);
    gn_stats<<<BB * 4, 256, 0, stream>>>(p_s2, 128L * NN, 32, NN, 4, p_st);
    gn_out_transpose<<<dim3(NN / 64, BB), 256, 0, stream>>>(
        p_s2, gns2_w, gns2_b, p_st, (float*)d_out);
}

// Round 12
// 1696.663 us; speedup vs baseline: 4.3800x; 1.1768x over previous
//
#include <hip/hip_runtime.h>
#include <hip/hip_bf16.h>

namespace {

constexpr int BB = 16;
constexpr int NN = 4096;
constexpr int MM = 1024;

using f32x4  = __attribute__((ext_vector_type(4))) float;
using bf16x8 = __attribute__((ext_vector_type(8))) short;

__device__ __forceinline__ float actf(float x, int act) {
    if (act == 1) return fmaxf(x, 0.f);
    if (act == 2) return x >= 0.f ? x : 0.2f * x;
    return x;
}

__device__ __forceinline__ ushort f2bf(float x) {
    __hip_bfloat16 h = __float2bfloat16(x);
    return *reinterpret_cast<ushort*>(&h);
}

// pack x as (hi_bf16 | lo_bf16<<16); x == hi + lo to ~2^-18 relative
__device__ __forceinline__ uint hilo_pack(float x) {
    ushort h = f2bf(x);
    float hf = __uint_as_float(((uint)h) << 16);
    ushort l = f2bf(x - hf);
    return (uint)h | ((uint)l << 16);
}

// 8 packed dwords -> hi bf16x8, lo bf16x8
__device__ __forceinline__ void split8(const uint* d, bf16x8& hi, bf16x8& lo) {
    union { uint u[4]; bf16x8 v; } H, L;
#pragma unroll
    for (int j = 0; j < 4; ++j) {
        H.u[j] = (d[2 * j] & 0xffffu) | (d[2 * j + 1] << 16);
        L.u[j] = (d[2 * j] >> 16) | (d[2 * j + 1] & 0xffff0000u);
    }
    hi = H.v; lo = L.v;
}

// ---------------------------------------------------------------------------
// MFMA pointwise-conv, split-precision bf16 (hi/lo, 3 MFMA -> ~fp32 accuracy).
// Y[b][o][l] = sum_c W[o][c] X[b][c][l] (+ sum_{c<3} W2[o][c] X2[b][c][l]) (+bias)
// C must be a multiple of 32. Tile 64o x 128l, 4 waves (2x2), K-tile 32.
// ---------------------------------------------------------------------------
__global__ __launch_bounds__(256)
void conv_mfma(const float* __restrict__ X, int C, long x_bs,
               const float* __restrict__ W,
               const float* __restrict__ X2, long x2_bs,
               const float* __restrict__ W2,
               const float* __restrict__ bias,
               float* __restrict__ Y, long y_bs, int L)
{
    __shared__ uint Wp[64 * 33];     //  8,448 B packed (hi,lo)
    __shared__ uint Xp[128 * 33];    // 16,896 B packed, transposed [l][c]
    const int t  = threadIdx.x;
    const int b  = blockIdx.z;
    const int o0 = blockIdx.y * 64;
    const int l0 = blockIdx.x * 128;
    const int w  = t >> 6;
    const int ln = t & 15;
    const int lq = (t >> 4) & 3;
    const int wo = (w & 1) * 32;     // wave o-offset
    const int wl = (w >> 1) * 64;    // wave l-offset
    const int sl  = t & 127;         // staging column (l)
    const int sch = (t >> 7) * 16;   // staging c-range start

    f32x4 acc[2][4];
#pragma unroll
    for (int i = 0; i < 2; ++i)
#pragma unroll
        for (int j = 0; j < 4; ++j) acc[i][j] = (f32x4){0.f, 0.f, 0.f, 0.f};

    for (int c0 = 0; c0 < C; c0 += 32) {
        __syncthreads();
        // stage W[64][32] -> packed hi/lo
#pragma unroll
        for (int i = 0; i < 2; ++i) {
            int f = i * 256 + t;
            int r = f >> 3, q4 = (f & 7) * 4;
            float4 wv = *reinterpret_cast<const float4*>(&W[(long)(o0 + r) * C + c0 + q4]);
            Wp[r * 33 + q4 + 0] = hilo_pack(wv.x);
            Wp[r * 33 + q4 + 1] = hilo_pack(wv.y);
            Wp[r * 33 + q4 + 2] = hilo_pack(wv.z);
            Wp[r * 33 + q4 + 3] = hilo_pack(wv.w);
        }
        // stage X[32][128] transposed: thread reads a 16-deep column (coalesced
        // across lanes), writes contiguous b128 rows of Xp
        {
            const float* xc = X + (long)b * x_bs + (long)(c0 + sch) * L + l0 + sl;
            uint tmp[16];
#pragma unroll
            for (int c = 0; c < 16; ++c) tmp[c] = hilo_pack(xc[(long)c * L]);
#pragma unroll
            for (int c4 = 0; c4 < 4; ++c4) {
                uint4 v = make_uint4(tmp[c4 * 4], tmp[c4 * 4 + 1],
                                     tmp[c4 * 4 + 2], tmp[c4 * 4 + 3]);
                *reinterpret_cast<uint4*>(&Xp[sl * 33 + sch + c4 * 4]) = v;
            }
        }
        __syncthreads();

        bf16x8 ahi[2], alo[2];
#pragma unroll
        for (int ot = 0; ot < 2; ++ot) {
            uint d[8];
            *reinterpret_cast<uint4*>(d) =
                *reinterpret_cast<const uint4*>(&Wp[(wo + ot * 16 + ln) * 33 + lq * 8]);
            *reinterpret_cast<uint4*>(d + 4) =
                *reinterpret_cast<const uint4*>(&Wp[(wo + ot * 16 + ln) * 33 + lq * 8 + 4]);
            split8(d, ahi[ot], alo[ot]);
        }
#pragma unroll
        for (int lt = 0; lt < 4; ++lt) {
            uint d[8];
            *reinterpret_cast<uint4*>(d) =
                *reinterpret_cast<const uint4*>(&Xp[(wl + lt * 16 + ln) * 33 + lq * 8]);
            *reinterpret_cast<uint4*>(d + 4) =
                *reinterpret_cast<const uint4*>(&Xp[(wl + lt * 16 + ln) * 33 + lq * 8 + 4]);
            bf16x8 bhi, blo;
            split8(d, bhi, blo);
#pragma unroll
            for (int ot = 0; ot < 2; ++ot) {
                acc[ot][lt] = __builtin_amdgcn_mfma_f32_16x16x32_bf16(alo[ot], bhi, acc[ot][lt], 0, 0, 0);
                acc[ot][lt] = __builtin_amdgcn_mfma_f32_16x16x32_bf16(ahi[ot], blo, acc[ot][lt], 0, 0, 0);
                acc[ot][lt] = __builtin_amdgcn_mfma_f32_16x16x32_bf16(ahi[ot], bhi, acc[ot][lt], 0, 0, 0);
            }
        }
    }

    // epilogue: bias + optional 3-channel positional term, coalesced stores
    float x2v[4][3];
    if (X2) {
#pragma unroll
        for (int lt = 0; lt < 4; ++lt) {
            const int l = l0 + wl + lt * 16 + ln;
#pragma unroll
            for (int c = 0; c < 3; ++c)
                x2v[lt][c] = X2[(long)b * x2_bs + (long)c * L + l];
        }
    }
#pragma unroll
    for (int ot = 0; ot < 2; ++ot)
#pragma unroll
        for (int r = 0; r < 4; ++r) {
            const int o = o0 + wo + ot * 16 + lq * 4 + r;
            float base = bias ? bias[o] : 0.f;
            float w20 = 0.f, w21 = 0.f, w22 = 0.f;
            if (X2) {
                w20 = W2[o * 3 + 0];
                w21 = W2[o * 3 + 1];
                w22 = W2[o * 3 + 2];
            }
#pragma unroll
            for (int lt = 0; lt < 4; ++lt) {
                const int l = l0 + wl + lt * 16 + ln;
                float val = acc[ot][lt][r] + base;
                if (X2)
                    val += w20 * x2v[lt][0] + w21 * x2v[lt][1] + w22 * x2v[lt][2];
                Y[(long)b * y_bs + (long)o * L + l] = val;
            }
        }
}

// ---------------------------------------------------------------------------
// Old fp32 conv (kept only for conv1, C=6 not divisible by 32)
// ---------------------------------------------------------------------------
__global__ __launch_bounds__(256)
void conv_gemm(const float* __restrict__ X1, int C1, long x1_bs,
               const float* __restrict__ W1,
               const float* __restrict__ X2, int C2, long x2_bs,
               const float* __restrict__ W2,
               const float* __restrict__ bias,
               float* __restrict__ Y, long y_bs, int L)
{
    __shared__ float Wt[64][17];
    __shared__ float Xt[16][128];
    const int t  = threadIdx.x;
    const int b  = blockIdx.z;
    const int o0 = blockIdx.y * 64;
    const int l0 = blockIdx.x * 128;
    const int ty = t >> 4, tx = t & 15;

    float acc[4][8];
#pragma unroll
    for (int i = 0; i < 4; ++i)
#pragma unroll
        for (int j = 0; j < 8; ++j) acc[i][j] = 0.f;

    for (int pass = 0; pass < 2; ++pass) {
        const float* X = pass ? X2 : X1;
        const float* W = pass ? W2 : W1;
        const int    C = pass ? C2 : C1;
        const long xbs = pass ? x2_bs : x1_bs;
        if (C <= 0 || X == nullptr) continue;
        for (int c0 = 0; c0 < C; c0 += 16) {
            __syncthreads();
#pragma unroll
            for (int i = 0; i < 4; ++i) {
                int flat = i * 256 + t;
                int oo = flat >> 4, kk = flat & 15;
                Wt[oo][kk] = (c0 + kk < C) ? W[(long)(o0 + oo) * C + c0 + kk] : 0.f;
            }
#pragma unroll
            for (int i = 0; i < 2; ++i) {
                int f4 = i * 256 + t;
                int kk = f4 >> 5, c4 = f4 & 31;
                float4 xv = make_float4(0.f, 0.f, 0.f, 0.f);
                if (c0 + kk < C)
                    xv = *reinterpret_cast<const float4*>(
                        X + (long)b * xbs + (long)(c0 + kk) * L + l0 + c4 * 4);
                *reinterpret_cast<float4*>(&Xt[kk][c4 * 4]) = xv;
            }
            __syncthreads();
#pragma unroll
            for (int kk = 0; kk < 16; ++kk) {
                float wv[4];
#pragma unroll
                for (int i = 0; i < 4; ++i) wv[i] = Wt[ty * 4 + i][kk];
                float4 xa = *reinterpret_cast<const float4*>(&Xt[kk][tx * 8]);
                float4 xb = *reinterpret_cast<const float4*>(&Xt[kk][tx * 8 + 4]);
                float xv[8] = {xa.x, xa.y, xa.z, xa.w, xb.x, xb.y, xb.z, xb.w};
#pragma unroll
                for (int i = 0; i < 4; ++i)
#pragma unroll
                    for (int j = 0; j < 8; ++j) acc[i][j] += wv[i] * xv[j];
            }
        }
    }

#pragma unroll
    for (int i = 0; i < 4; ++i) {
        const int oo = o0 + ty * 4 + i;
        const float bv = bias ? bias[oo] : 0.f;
        float* yp = Y + (long)b * y_bs + (long)oo * L + l0 + tx * 8;
        float4 v0 = make_float4(acc[i][0] + bv, acc[i][1] + bv, acc[i][2] + bv, acc[i][3] + bv);
        float4 v1 = make_float4(acc[i][4] + bv, acc[i][5] + bv, acc[i][6] + bv, acc[i][7] + bv);
        *reinterpret_cast<float4*>(yp)     = v0;
        *reinterpret_cast<float4*>(yp + 4) = v1;
    }
}

// ---------------------------------------------------------------------------
// GroupNorm stats / apply (unchanged)
// ---------------------------------------------------------------------------
__global__ __launch_bounds__(256)
void gn_stats(const float* __restrict__ Y, long y_bs, int cpg, int L, int G,
              float* __restrict__ stats)
{
    const int bg = blockIdx.x;
    const int b = bg / G, g = bg - b * G;
    const float* p = Y + (long)b * y_bs + (long)g * cpg * L;
    const long cnt = (long)cpg * L;
    float s = 0.f, ss = 0.f;
    for (long i = (long)threadIdx.x * 4; i < cnt; i += 256 * 4) {
        float4 v = *reinterpret_cast<const float4*>(p + i);
        s  += v.x + v.y + v.z + v.w;
        ss += v.x * v.x + v.y * v.y + v.z * v.z + v.w * v.w;
    }
    __shared__ float rs[256], rss[256];
    rs[threadIdx.x] = s; rss[threadIdx.x] = ss;
    __syncthreads();
    for (int st = 128; st > 0; st >>= 1) {
        if (threadIdx.x < st) {
            rs[threadIdx.x]  += rs[threadIdx.x + st];
            rss[threadIdx.x] += rss[threadIdx.x + st];
        }
        __syncthreads();
    }
    if (threadIdx.x == 0) {
        float mu  = rs[0] / (float)cnt;
        float var = rss[0] / (float)cnt - mu * mu;
        stats[bg * 2]     = mu;
        stats[bg * 2 + 1] = rsqrtf(var + 1e-5f);
    }
}

__global__ __launch_bounds__(256)
void gn_apply(const float* __restrict__ src, long s_bs,
              float* __restrict__ dst, long d_bs,
              const float* __restrict__ res, long r_bs,
              const float* __restrict__ w, const float* __restrict__ bb,
              const float* __restrict__ stats,
              int C, int cpg, int L, int act)
{
    const long total4 = (long)BB * C * L / 4;
    const int G = C / cpg;
    for (long i4 = (long)blockIdx.x * 256 + threadIdx.x; i4 < total4;
         i4 += (long)gridDim.x * 256) {
        long flat = i4 * 4;
        int b = (int)(flat / ((long)C * L));
        long rem = flat - (long)b * C * L;
        int c = (int)(rem / L);
        long li = rem - (long)c * L;
        int sidx = (b * G + c / cpg) * 2;
        float mu = stats[sidx], rsig = stats[sidx + 1];
        float sc = rsig * w[c];
        float sh = bb[c] - mu * sc;
        float4 vv = *reinterpret_cast<const float4*>(src + (long)b * s_bs + (long)c * L + li);
        float4 ov;
        ov.x = actf(vv.x * sc + sh, act);
        ov.y = actf(vv.y * sc + sh, act);
        ov.z = actf(vv.z * sc + sh, act);
        ov.w = actf(vv.w * sc + sh, act);
        if (res) {
            float4 rv = *reinterpret_cast<const float4*>(res + (long)b * r_bs + (long)c * L + li);
            ov.x += rv.x; ov.y += rv.y; ov.z += rv.z; ov.w += rv.w;
        }
        *reinterpret_cast<float4*>(dst + (long)b * d_bs + (long)c * L + li) = ov;
    }
}

// ---------------------------------------------------------------------------
// Transpose+convert: in [B][64][L] f32 -> out [B][L][64] bf16 (unchanged)
// ---------------------------------------------------------------------------
__global__ __launch_bounds__(256)
void tcvt(const float* __restrict__ in, ushort* __restrict__ out, int L)
{
    __shared__ float ls[64][65];
    const int t = threadIdx.x, b = blockIdx.y;
    const int l0 = blockIdx.x * 64;
#pragma unroll
    for (int i = 0; i < 16; ++i) {
        int f = i * 256 + t;
        int d = f >> 6, l = f & 63;
        ls[d][l] = in[(long)b * 64 * L + (long)d * L + l0 + l];
    }
    __syncthreads();
#pragma unroll
    for (int i = 0; i < 16; ++i) {
        int f = i * 256 + t;
        int l = f >> 6, d = f & 63;
        out[((long)b * L + l0 + l) * 64 + d] = f2bf(ls[d][l]);
    }
}

// ---------------------------------------------------------------------------
// MFMA attention phase 0 (unchanged from round 11)
// ---------------------------------------------------------------------------
__global__ __launch_bounds__(256)
void attn_stats_mfma(const ushort* __restrict__ qt, const ushort* __restrict__ kt,
                     float* __restrict__ rowmax, float* __restrict__ rowinv,
                     float* __restrict__ csp)
{
    __shared__ float red[16][5];
    __shared__ float rs_mx[16], rs_inv[16];

    const int t  = threadIdx.x;
    const int b  = blockIdx.y;
    const int n0 = blockIdx.x * 16;
    const int w  = t >> 6;
    const int ln = t & 15;
    const int lq = (t >> 4) & 3;

    const ushort* qtb = qt + ((long)b * NN + n0) * 64;
    const ushort* ktb = kt + (long)b * MM * 64;

    bf16x8 aq[2];
#pragma unroll
    for (int ks = 0; ks < 2; ++ks)
        aq[ks] = *reinterpret_cast<const bf16x8*>(qtb + (long)ln * 64 + ks * 32 + lq * 8);

    f32x4 sc[16];
#pragma unroll
    for (int i = 0; i < 16; ++i) {
        const int m0 = (w * 16 + i) * 16;
        f32x4 acc = {0.f, 0.f, 0.f, 0.f};
#pragma unroll
        for (int ks = 0; ks < 2; ++ks) {
            bf16x8 bk = *reinterpret_cast<const bf16x8*>(
                ktb + (long)(m0 + ln) * 64 + ks * 32 + lq * 8);
            acc = __builtin_amdgcn_mfma_f32_16x16x32_bf16(aq[ks], bk, acc, 0, 0, 0);
        }
        sc[i] = acc;
    }

    float m4[4];
#pragma unroll
    for (int r = 0; r < 4; ++r) {
        float mx = sc[0][r];
#pragma unroll
        for (int i = 1; i < 16; ++i) mx = fmaxf(mx, sc[i][r]);
#pragma unroll
        for (int off = 1; off <= 8; off <<= 1) mx = fmaxf(mx, __shfl_xor(mx, off, 64));
        m4[r] = mx;
    }
    if (ln == 0)
#pragma unroll
        for (int r = 0; r < 4; ++r) red[lq * 4 + r][w] = m4[r];
    __syncthreads();
    if (t < 16) {
        float mx = fmaxf(fmaxf(red[t][0], red[t][1]), fmaxf(red[t][2], red[t][3]));
        rs_mx[t] = mx;
        rowmax[(long)b * NN + n0 + t] = mx;
    }
    __syncthreads();

    float mxr[4], s4[4];
#pragma unroll
    for (int r = 0; r < 4; ++r) { mxr[r] = rs_mx[lq * 4 + r]; s4[r] = 0.f; }
#pragma unroll
    for (int i = 0; i < 16; ++i)
#pragma unroll
        for (int r = 0; r < 4; ++r) {
            float e = __expf(sc[i][r] - mxr[r]);
            sc[i][r] = e;
            s4[r] += e;
        }
#pragma unroll
    for (int r = 0; r < 4; ++r)
#pragma unroll
        for (int off = 1; off <= 8; off <<= 1) s4[r] += __shfl_xor(s4[r], off, 64);
    if (ln == 0)
#pragma unroll
        for (int r = 0; r < 4; ++r) red[lq * 4 + r][w] = s4[r];
    __syncthreads();
    if (t < 16) {
        float es = red[t][0] + red[t][1] + red[t][2] + red[t][3];
        float inv = 1.0f / es;
        rs_inv[t] = inv;
        rowinv[(long)b * NN + n0 + t] = inv;
    }
    __syncthreads();

    float riv[4];
#pragma unroll
    for (int r = 0; r < 4; ++r) riv[r] = rs_inv[lq * 4 + r];
    const long cbase = ((long)b * (NN / 16) + blockIdx.x) * MM;
#pragma unroll
    for (int i = 0; i < 16; ++i) {
        float c = sc[i][0] * riv[0] + sc[i][1] * riv[1] + sc[i][2] * riv[2] + sc[i][3] * riv[3];
        c += __shfl_xor(c, 16, 64);
        c += __shfl_xor(c, 32, 64);
        if (lq == 0) csp[cbase + (w * 16 + i) * 16 + ln] = c;
    }
}

// ---------------------------------------------------------------------------
// MFMA attention phase 1 (unchanged from round 11)
// ---------------------------------------------------------------------------
__global__ __launch_bounds__(256)
void attn_pv_mfma(const ushort* __restrict__ qt, const ushort* __restrict__ kt,
                  const ushort* __restrict__ vb,
                  const float* __restrict__ rowmax, const float* __restrict__ rowinv,
                  const float* __restrict__ qg, float* __restrict__ ug)
{
    __shared__ ushort Pb[16 * 1024];

    const int t  = threadIdx.x;
    const int b  = blockIdx.y;
    const int n0 = blockIdx.x * 16;
    const int w  = t >> 6;
    const int ln = t & 15;
    const int lq = (t >> 4) & 3;

    const ushort* qtb = qt + ((long)b * NN + n0) * 64;
    const ushort* ktb = kt + (long)b * MM * 64;

    float mx[4], ri[4];
#pragma unroll
    for (int r = 0; r < 4; ++r) {
        mx[r] = rowmax[(long)b * NN + n0 + lq * 4 + r];
        ri[r] = rowinv[(long)b * NN + n0 + lq * 4 + r];
    }

    bf16x8 aq[2];
#pragma unroll
    for (int ks = 0; ks < 2; ++ks)
        aq[ks] = *reinterpret_cast<const bf16x8*>(qtb + (long)ln * 64 + ks * 32 + lq * 8);

#pragma unroll
    for (int i = 0; i < 16; ++i) {
        const int m0 = (w * 16 + i) * 16;
        f32x4 acc = {0.f, 0.f, 0.f, 0.f};
#pragma unroll
        for (int ks = 0; ks < 2; ++ks) {
            bf16x8 bk = *reinterpret_cast<const bf16x8*>(
                ktb + (long)(m0 + ln) * 64 + ks * 32 + lq * 8);
            acc = __builtin_amdgcn_mfma_f32_16x16x32_bf16(aq[ks], bk, acc, 0, 0, 0);
        }
#pragma unroll
        for (int r = 0; r < 4; ++r) {
            const int n = lq * 4 + r;
            float p = __expf(acc[r] - mx[r]) * ri[r];
            Pb[n * 1024 + ((m0 + ln) ^ ((n & 7) << 3))] = f2bf(p);
        }
    }
    __syncthreads();

    const ushort* vbb = vb + (long)b * 64 * MM;
    const int d0 = w * 16;
    f32x4 acc = {0.f, 0.f, 0.f, 0.f};
#pragma unroll 8
    for (int ks = 0; ks < 32; ++ks) {
        bf16x8 av = *reinterpret_cast<const bf16x8*>(
            vbb + (long)(d0 + ln) * MM + ks * 32 + lq * 8);
        bf16x8 bp = *reinterpret_cast<const bf16x8*>(
            &Pb[ln * 1024 + ((ks * 32 + lq * 8) ^ ((ln & 7) << 3))]);
        acc = __builtin_amdgcn_mfma_f32_16x16x32_bf16(av, bp, acc, 0, 0, 0);
    }

    const long qb = (long)b * 64 * NN;
#pragma unroll
    for (int r = 0; r < 4; ++r) {
        const int dd = d0 + lq * 4 + r;
        const long idx = qb + (long)dd * NN + n0 + ln;
        ug[idx] = qg[idx] - acc[r];
    }
}

__global__ __launch_bounds__(256)
void colsum_reduce(const float* __restrict__ csp, float* __restrict__ cs, int NT)
{
    int idx = blockIdx.x * 256 + threadIdx.x;   // over B*M
    int b = idx / MM, m = idx - b * MM;
    const float* p = csp + (long)b * NT * MM + m;
    float s = 0.f;
    for (int i = 0; i < NT; ++i) s += p[(long)i * MM];
    cs[idx] = s;
}

__global__ __launch_bounds__(256)
void vscale_cvt(const float* __restrict__ v, const float* __restrict__ cs,
                ushort* __restrict__ vb)
{
    long i4 = (long)blockIdx.x * 256 + threadIdx.x;
    long flat = i4 * 4;                          // index into [B][64][M]
    int b = (int)(flat / (64L * MM));
    int m = (int)(flat % MM);
    float4 vv = *reinterpret_cast<const float4*>(v + flat);
    float4 cv = *reinterpret_cast<const float4*>(cs + (long)b * MM + m);
    ushort4 o;
    o.x = f2bf(vv.x / (1e-9f + cv.x));
    o.y = f2bf(vv.y / (1e-9f + cv.y));
    o.z = f2bf(vv.z / (1e-9f + cv.z));
    o.w = f2bf(vv.w / (1e-9f + cv.w));
    *reinterpret_cast<ushort4*>(vb + flat) = o;
}

// ---------------------------------------------------------------------------
// Final GN4 + relu + transpose (unchanged)
// ---------------------------------------------------------------------------
__global__ __launch_bounds__(256)
void gn_out_transpose(const float* __restrict__ s2,
                      const float* __restrict__ w, const float* __restrict__ bb,
                      const float* __restrict__ stats,
                      float* __restrict__ out)
{
    __shared__ float ls[128 * 65];
    const int t = threadIdx.x;
    const int b = blockIdx.y;
    const int n0 = blockIdx.x * 64;
#pragma unroll
    for (int i = 0; i < 8; ++i) {
        int f4 = i * 256 + t;
        int o = f4 >> 4, c4 = f4 & 15;
        float4 vv = *reinterpret_cast<const float4*>(
            s2 + (long)b * 128 * NN + (long)o * NN + n0 + c4 * 4);
        int sidx = (b * 4 + (o >> 5)) * 2;
        float mu = stats[sidx], rsig = stats[sidx + 1];
        float sc = rsig * w[o], sh = bb[o] - mu * sc;
        ls[o * 65 + c4 * 4 + 0] = fmaxf(vv.x * sc + sh, 0.f);
        ls[o * 65 + c4 * 4 + 1] = fmaxf(vv.y * sc + sh, 0.f);
        ls[o * 65 + c4 * 4 + 2] = fmaxf(vv.z * sc + sh, 0.f);
        ls[o * 65 + c4 * 4 + 3] = fmaxf(vv.w * sc + sh, 0.f);
    }
    __syncthreads();
#pragma unroll
    for (int i = 0; i < 8; ++i) {
        int f4 = i * 256 + t;
        int nn = f4 >> 5, o4 = f4 & 31;
        float4 ov;
        ov.x = ls[(o4 * 4 + 0) * 65 + nn];
        ov.y = ls[(o4 * 4 + 1) * 65 + nn];
        ov.z = ls[(o4 * 4 + 2) * 65 + nn];
        ov.w = ls[(o4 * 4 + 3) * 65 + nn];
        *reinterpret_cast<float4*>(out + (long)b * NN * 128 + (long)(n0 + nn) * 128 + o4 * 4) = ov;
    }
}

} // namespace

extern "C" void kernel_launch(void* const* d_in, const int* in_sizes, int n_in,
                              void* d_out, int out_size, void* d_ws, size_t ws_size,
                              hipStream_t stream)
{
    (void)in_sizes; (void)n_in; (void)out_size; (void)ws_size;

    const float* x         = (const float*)d_in[0];
    const float* x_global  = (const float*)d_in[1];
    const float* xyz       = (const float*)d_in[2];
    const float* xyz_g     = (const float*)d_in[3];
    const float* conv1_w   = (const float*)d_in[4];
    const float* gn1_w     = (const float*)d_in[5];
    const float* gn1_b     = (const float*)d_in[6];
    const float* conv2_w   = (const float*)d_in[7];
    const float* gn2_w     = (const float*)d_in[8];
    const float* gn2_b     = (const float*)d_in[9];
    const float* sa_qk_w   = (const float*)d_in[10];
    const float* sa_v_w    = (const float*)d_in[11];
    const float* sa_v_b    = (const float*)d_in[12];
    const float* sa_t_w    = (const float*)d_in[13];
    const float* sa_t_b    = (const float*)d_in[14];
    const float* sa_gn_w   = (const float*)d_in[15];
    const float* sa_gn_b   = (const float*)d_in[16];
    const float* sa_pos_w  = (const float*)d_in[17];
    const float* sa_posG_w = (const float*)d_in[18];
    const float* fuse_w    = (const float*)d_in[19];
    const float* fuse_gn_w = (const float*)d_in[20];
    const float* fuse_gn_b = (const float*)d_in[21];
    const float* convs1_w  = (const float*)d_in[22];
    const float* convs1_b  = (const float*)d_in[23];
    const float* gns1_w    = (const float*)d_in[24];
    const float* gns1_b    = (const float*)d_in[25];
    const float* convs2_w  = (const float*)d_in[26];
    const float* convs2_b  = (const float*)d_in[27];
    const float* gns2_w    = (const float*)d_in[28];
    const float* gns2_b    = (const float*)d_in[29];

    // ---- workspace layout; identical to round 11 (proven) ----
    constexpr long SZ_BN  = (long)BB * 64 * NN;
    constexpr long SZ_BM  = (long)BB * 64 * MM;
    constexpr long SZ_CSP = (long)BB * (NN / 16) * MM;

    float* ws = (float*)d_ws;
    long o = 0;
    float* p_h   = ws + o; o += SZ_BN;
    float* p_hg  = ws + o; o += SZ_BM;
    float* p_q   = ws + o; o += SZ_BN;
    float* p_k   = ws + o; o += SZ_BM;
    float* p_v   = ws + o; o += SZ_BM;
    float* p_u   = ws + o; o += SZ_BN;
    float* p_csp = ws + o; o += SZ_CSP;
    float* p_cs  = ws + o; o += (long)BB * MM;
    float* p_xc  = ws + o; o += (long)BB * 256 * NN;
    float* p_xf  = ws + o; o += (long)BB * 128 * NN;
    float* p_st  = ws + o; o += 4096;
    float* p_rmx = ws + o; o += (long)BB * NN;
    float* p_rin = ws + o; o += (long)BB * NN;
    float* p_s1  = ws;
    float* p_s2  = p_xf;
    ushort* p_qt = (ushort*)p_xf;
    ushort* p_kt = (ushort*)(p_xf + 2097152);
    ushort* p_vb = (ushort*)(p_xf + 2097152 + 524288);

    // h = relu(GN16(conv1(x)))   (C=6 -> old kernel)
    conv_gemm<<<dim3(NN / 128, 1, BB), 256, 0, stream>>>(
        x, 6, 6L * NN, conv1_w, nullptr, 0, 0, nullptr, nullptr, p_h, 64L * NN, NN);
    gn_stats<<<BB * 16, 256, 0, stream>>>(p_h, 64L * NN, 4, NN, 16, p_st);
    gn_apply<<<2048, 256, 0, stream>>>(p_h, 64L * NN, p_h, 64L * NN, nullptr, 0,
                                       gn1_w, gn1_b, p_st, 64, 4, NN, 1);
    // hg = relu(GN16(conv2(x_global)))   (C=32 -> MFMA)
    conv_mfma<<<dim3(MM / 128, 1, BB), 256, 0, stream>>>(
        x_global, 32, 32L * MM, conv2_w, nullptr, 0, nullptr, nullptr, p_hg, 64L * MM, MM);
    gn_stats<<<BB * 16, 256, 0, stream>>>(p_hg, 64L * MM, 4, MM, 16, p_st);
    gn_apply<<<2048, 256, 0, stream>>>(p_hg, 64L * MM, p_hg, 64L * MM, nullptr, 0,
                                       gn2_w, gn2_b, p_st, 64, 4, MM, 1);

    const float* cur = p_h;
    long cur_bs = 64L * NN;
    for (int i = 0; i < 4; ++i) {
        // q = qk_w*cur + pos_w*xyz
        conv_mfma<<<dim3(NN / 128, 1, BB), 256, 0, stream>>>(
            cur, 64, cur_bs, sa_qk_w + i * 4096,
            xyz, 3L * NN, sa_pos_w + i * 192, nullptr, p_q, 64L * NN, NN);
        tcvt<<<dim3(NN / 64, BB), 256, 0, stream>>>(p_q, p_qt, NN);
        // k = qk_w*hg + posG_w*xyz_g
        conv_mfma<<<dim3(MM / 128, 1, BB), 256, 0, stream>>>(
            p_hg, 64, 64L * MM, sa_qk_w + i * 4096,
            xyz_g, 3L * MM, sa_posG_w + i * 192, nullptr, p_k, 64L * MM, MM);
        tcvt<<<dim3(MM / 64, BB), 256, 0, stream>>>(p_k, p_kt, MM);
        // v = v_w*hg + posG_w*xyz_g + v_b
        conv_mfma<<<dim3(MM / 128, 1, BB), 256, 0, stream>>>(
            p_hg, 64, 64L * MM, sa_v_w + i * 4096,
            xyz_g, 3L * MM, sa_posG_w + i * 192, sa_v_b + i * 64, p_v, 64L * MM, MM);
        // phase 0: MFMA softmax stats + column partials
        attn_stats_mfma<<<dim3(NN / 16, BB), 256, 0, stream>>>(p_qt, p_kt, p_rmx, p_rin, p_csp);
        colsum_reduce<<<BB * MM / 256, 256, 0, stream>>>(p_csp, p_cs, NN / 16);
        vscale_cvt<<<BB * 64 * MM / 1024, 256, 0, stream>>>(p_v, p_cs, p_vb);
        // phase 1: u = q - P*v'
        attn_pv_mfma<<<dim3(NN / 16, BB), 256, 0, stream>>>(
            p_qt, p_kt, p_vb, p_rmx, p_rin, p_q, p_u);
        // t = t_w*u + t_b
        conv_mfma<<<dim3(NN / 128, 1, BB), 256, 0, stream>>>(
            p_u, 64, 64L * NN, sa_t_w + i * 4096,
            nullptr, 0, nullptr, sa_t_b + i * 64, p_h, 64L * NN, NN);
        // out_i = q + relu(GN4(t))  -> xc slice i
        gn_stats<<<BB * 4, 256, 0, stream>>>(p_h, 64L * NN, 16, NN, 4, p_st);
        gn_apply<<<2048, 256, 0, stream>>>(p_h, 64L * NN,
                                           p_xc + (long)i * 64 * NN, 256L * NN,
                                           p_q, 64L * NN,
                                           sa_gn_w + i * 64, sa_gn_b + i * 64, p_st,
                                           64, 16, NN, 1);
        cur = p_xc + (long)i * 64 * NN;
        cur_bs = 256L * NN;
    }

    // xf = leaky(GN16(fuse_w * xc))
    conv_mfma<<<dim3(NN / 128, 2, BB), 256, 0, stream>>>(
        p_xc, 256, 256L * NN, fuse_w, nullptr, 0, nullptr, nullptr, p_xf, 128L * NN, NN);
    gn_stats<<<BB * 16, 256, 0, stream>>>(p_xf, 128L * NN, 8, NN, 16, p_st);
    gn_apply<<<2048, 256, 0, stream>>>(p_xf, 128L * NN, p_xf, 128L * NN, nullptr, 0,
                                       fuse_gn_w, fuse_gn_b, p_st, 128, 8, NN, 2);
    // s1 = relu(GN8(convs1_w * xf + b))
    conv_mfma<<<dim3(NN / 128, 8, BB), 256, 0, stream>>>(
        p_xf, 128, 128L * NN, convs1_w, nullptr, 0, nullptr, convs1_b, p_s1, 512L * NN, NN);
    gn_stats<<<BB * 8, 256, 0, stream>>>(p_s1, 512L * NN, 64, NN, 8, p_st);
    gn_apply<<<2048, 256, 0, stream>>>(p_s1, 512L * NN, p_s1, 512L * NN, nullptr, 0,
                                       gns1_w, gns1_b, p_st, 512, 64, NN, 1);
    // s2 = GN4(convs2_w * s1 + b), relu fused into transpose
    conv_mfma<<<dim3(NN / 128, 2, BB), 256, 0, stream>>>(
        p_s1, 512, 512L * NN, convs2_w, nullptr, 0, nullptr, convs2_b, p_s2, 128L * NN, NN);
    gn_stats<<<BB * 4, 256, 0, stream>>>(p_s2, 128L * NN, 32, NN, 4, p_st);
    gn_out_transpose<<<dim3(NN / 64, BB), 256, 0, stream>>>(
        p_s2, gns2_w, gns2_b, p_st, (float*)d_out);
}

// Round 13
// 1581.964 us; speedup vs baseline: 4.6975x; 1.0725x over previous
//
#include <hip/hip_runtime.h>
#include <hip/hip_bf16.h>

namespace {

constexpr int BB = 16;
constexpr int NN = 4096;
constexpr int MM = 1024;

using f32x4  = __attribute__((ext_vector_type(4))) float;
using bf16x8 = __attribute__((ext_vector_type(8))) short;

__device__ __forceinline__ float actf(float x, int act) {
    if (act == 1) return fmaxf(x, 0.f);
    if (act == 2) return x >= 0.f ? x : 0.2f * x;
    return x;
}

__device__ __forceinline__ ushort f2bf(float x) {
    __hip_bfloat16 h = __float2bfloat16(x);
    return *reinterpret_cast<ushort*>(&h);
}

// pack x as (hi_bf16 | lo_bf16<<16); x == hi + lo to ~2^-18 relative
__device__ __forceinline__ uint hilo_pack(float x) {
    ushort h = f2bf(x);
    float hf = __uint_as_float(((uint)h) << 16);
    ushort l = f2bf(x - hf);
    return (uint)h | ((uint)l << 16);
}

// 8 packed dwords -> hi bf16x8, lo bf16x8
__device__ __forceinline__ void split8(const uint* d, bf16x8& hi, bf16x8& lo) {
    union { uint u[4]; bf16x8 v; } H, L;
#pragma unroll
    for (int j = 0; j < 4; ++j) {
        H.u[j] = (d[2 * j] & 0xffffu) | (d[2 * j + 1] << 16);
        L.u[j] = (d[2 * j] >> 16) | (d[2 * j + 1] & 0xffff0000u);
    }
    hi = H.v; lo = L.v;
}

// ---------------------------------------------------------------------------
// MFMA pointwise-conv, split-precision bf16 (unchanged from round 12)
// ---------------------------------------------------------------------------
__global__ __launch_bounds__(256)
void conv_mfma(const float* __restrict__ X, int C, long x_bs,
               const float* __restrict__ W,
               const float* __restrict__ X2, long x2_bs,
               const float* __restrict__ W2,
               const float* __restrict__ bias,
               float* __restrict__ Y, long y_bs, int L)
{
    __shared__ uint Wp[64 * 33];
    __shared__ uint Xp[128 * 33];
    const int t  = threadIdx.x;
    const int b  = blockIdx.z;
    const int o0 = blockIdx.y * 64;
    const int l0 = blockIdx.x * 128;
    const int w  = t >> 6;
    const int ln = t & 15;
    const int lq = (t >> 4) & 3;
    const int wo = (w & 1) * 32;
    const int wl = (w >> 1) * 64;
    const int sl  = t & 127;
    const int sch = (t >> 7) * 16;

    f32x4 acc[2][4];
#pragma unroll
    for (int i = 0; i < 2; ++i)
#pragma unroll
        for (int j = 0; j < 4; ++j) acc[i][j] = (f32x4){0.f, 0.f, 0.f, 0.f};

    for (int c0 = 0; c0 < C; c0 += 32) {
        __syncthreads();
#pragma unroll
        for (int i = 0; i < 2; ++i) {
            int f = i * 256 + t;
            int r = f >> 3, q4 = (f & 7) * 4;
            float4 wv = *reinterpret_cast<const float4*>(&W[(long)(o0 + r) * C + c0 + q4]);
            Wp[r * 33 + q4 + 0] = hilo_pack(wv.x);
            Wp[r * 33 + q4 + 1] = hilo_pack(wv.y);
            Wp[r * 33 + q4 + 2] = hilo_pack(wv.z);
            Wp[r * 33 + q4 + 3] = hilo_pack(wv.w);
        }
        {
            const float* xc = X + (long)b * x_bs + (long)(c0 + sch) * L + l0 + sl;
            uint tmp[16];
#pragma unroll
            for (int c = 0; c < 16; ++c) tmp[c] = hilo_pack(xc[(long)c * L]);
#pragma unroll
            for (int c4 = 0; c4 < 4; ++c4) {
                uint4 v = make_uint4(tmp[c4 * 4], tmp[c4 * 4 + 1],
                                     tmp[c4 * 4 + 2], tmp[c4 * 4 + 3]);
                *reinterpret_cast<uint4*>(&Xp[sl * 33 + sch + c4 * 4]) = v;
            }
        }
        __syncthreads();

        bf16x8 ahi[2], alo[2];
#pragma unroll
        for (int ot = 0; ot < 2; ++ot) {
            uint d[8];
            *reinterpret_cast<uint4*>(d) =
                *reinterpret_cast<const uint4*>(&Wp[(wo + ot * 16 + ln) * 33 + lq * 8]);
            *reinterpret_cast<uint4*>(d + 4) =
                *reinterpret_cast<const uint4*>(&Wp[(wo + ot * 16 + ln) * 33 + lq * 8 + 4]);
            split8(d, ahi[ot], alo[ot]);
        }
#pragma unroll
        for (int lt = 0; lt < 4; ++lt) {
            uint d[8];
            *reinterpret_cast<uint4*>(d) =
                *reinterpret_cast<const uint4*>(&Xp[(wl + lt * 16 + ln) * 33 + lq * 8]);
            *reinterpret_cast<uint4*>(d + 4) =
                *reinterpret_cast<const uint4*>(&Xp[(wl + lt * 16 + ln) * 33 + lq * 8 + 4]);
            bf16x8 bhi, blo;
            split8(d, bhi, blo);
#pragma unroll
            for (int ot = 0; ot < 2; ++ot) {
                acc[ot][lt] = __builtin_amdgcn_mfma_f32_16x16x32_bf16(alo[ot], bhi, acc[ot][lt], 0, 0, 0);
                acc[ot][lt] = __builtin_amdgcn_mfma_f32_16x16x32_bf16(ahi[ot], blo, acc[ot][lt], 0, 0, 0);
                acc[ot][lt] = __builtin_amdgcn_mfma_f32_16x16x32_bf16(ahi[ot], bhi, acc[ot][lt], 0, 0, 0);
            }
        }
    }

    float x2v[4][3];
    if (X2) {
#pragma unroll
        for (int lt = 0; lt < 4; ++lt) {
            const int l = l0 + wl + lt * 16 + ln;
#pragma unroll
            for (int c = 0; c < 3; ++c)
                x2v[lt][c] = X2[(long)b * x2_bs + (long)c * L + l];
        }
    }
#pragma unroll
    for (int ot = 0; ot < 2; ++ot)
#pragma unroll
        for (int r = 0; r < 4; ++r) {
            const int o = o0 + wo + ot * 16 + lq * 4 + r;
            float base = bias ? bias[o] : 0.f;
            float w20 = 0.f, w21 = 0.f, w22 = 0.f;
            if (X2) {
                w20 = W2[o * 3 + 0];
                w21 = W2[o * 3 + 1];
                w22 = W2[o * 3 + 2];
            }
#pragma unroll
            for (int lt = 0; lt < 4; ++lt) {
                const int l = l0 + wl + lt * 16 + ln;
                float val = acc[ot][lt][r] + base;
                if (X2)
                    val += w20 * x2v[lt][0] + w21 * x2v[lt][1] + w22 * x2v[lt][2];
                Y[(long)b * y_bs + (long)o * L + l] = val;
            }
        }
}

// ---------------------------------------------------------------------------
// Old fp32 conv (kept only for conv1, C=6)
// ---------------------------------------------------------------------------
__global__ __launch_bounds__(256)
void conv_gemm(const float* __restrict__ X1, int C1, long x1_bs,
               const float* __restrict__ W1,
               const float* __restrict__ X2, int C2, long x2_bs,
               const float* __restrict__ W2,
               const float* __restrict__ bias,
               float* __restrict__ Y, long y_bs, int L)
{
    __shared__ float Wt[64][17];
    __shared__ float Xt[16][128];
    const int t  = threadIdx.x;
    const int b  = blockIdx.z;
    const int o0 = blockIdx.y * 64;
    const int l0 = blockIdx.x * 128;
    const int ty = t >> 4, tx = t & 15;

    float acc[4][8];
#pragma unroll
    for (int i = 0; i < 4; ++i)
#pragma unroll
        for (int j = 0; j < 8; ++j) acc[i][j] = 0.f;

    for (int pass = 0; pass < 2; ++pass) {
        const float* X = pass ? X2 : X1;
        const float* W = pass ? W2 : W1;
        const int    C = pass ? C2 : C1;
        const long xbs = pass ? x2_bs : x1_bs;
        if (C <= 0 || X == nullptr) continue;
        for (int c0 = 0; c0 < C; c0 += 16) {
            __syncthreads();
#pragma unroll
            for (int i = 0; i < 4; ++i) {
                int flat = i * 256 + t;
                int oo = flat >> 4, kk = flat & 15;
                Wt[oo][kk] = (c0 + kk < C) ? W[(long)(o0 + oo) * C + c0 + kk] : 0.f;
            }
#pragma unroll
            for (int i = 0; i < 2; ++i) {
                int f4 = i * 256 + t;
                int kk = f4 >> 5, c4 = f4 & 31;
                float4 xv = make_float4(0.f, 0.f, 0.f, 0.f);
                if (c0 + kk < C)
                    xv = *reinterpret_cast<const float4*>(
                        X + (long)b * xbs + (long)(c0 + kk) * L + l0 + c4 * 4);
                *reinterpret_cast<float4*>(&Xt[kk][c4 * 4]) = xv;
            }
            __syncthreads();
#pragma unroll
            for (int kk = 0; kk < 16; ++kk) {
                float wv[4];
#pragma unroll
                for (int i = 0; i < 4; ++i) wv[i] = Wt[ty * 4 + i][kk];
                float4 xa = *reinterpret_cast<const float4*>(&Xt[kk][tx * 8]);
                float4 xb = *reinterpret_cast<const float4*>(&Xt[kk][tx * 8 + 4]);
                float xv[8] = {xa.x, xa.y, xa.z, xa.w, xb.x, xb.y, xb.z, xb.w};
#pragma unroll
                for (int i = 0; i < 4; ++i)
#pragma unroll
                    for (int j = 0; j < 8; ++j) acc[i][j] += wv[i] * xv[j];
            }
        }
    }

#pragma unroll
    for (int i = 0; i < 4; ++i) {
        const int oo = o0 + ty * 4 + i;
        const float bv = bias ? bias[oo] : 0.f;
        float* yp = Y + (long)b * y_bs + (long)oo * L + l0 + tx * 8;
        float4 v0 = make_float4(acc[i][0] + bv, acc[i][1] + bv, acc[i][2] + bv, acc[i][3] + bv);
        float4 v1 = make_float4(acc[i][4] + bv, acc[i][5] + bv, acc[i][6] + bv, acc[i][7] + bv);
        *reinterpret_cast<float4*>(yp)     = v0;
        *reinterpret_cast<float4*>(yp + 4) = v1;
    }
}

// ---------------------------------------------------------------------------
// GroupNorm stats / apply (unchanged)
// ---------------------------------------------------------------------------
__global__ __launch_bounds__(256)
void gn_stats(const float* __restrict__ Y, long y_bs, int cpg, int L, int G,
              float* __restrict__ stats)
{
    const int bg = blockIdx.x;
    const int b = bg / G, g = bg - b * G;
    const float* p = Y + (long)b * y_bs + (long)g * cpg * L;
    const long cnt = (long)cpg * L;
    float s = 0.f, ss = 0.f;
    for (long i = (long)threadIdx.x * 4; i < cnt; i += 256 * 4) {
        float4 v = *reinterpret_cast<const float4*>(p + i);
        s  += v.x + v.y + v.z + v.w;
        ss += v.x * v.x + v.y * v.y + v.z * v.z + v.w * v.w;
    }
    __shared__ float rs[256], rss[256];
    rs[threadIdx.x] = s; rss[threadIdx.x] = ss;
    __syncthreads();
    for (int st = 128; st > 0; st >>= 1) {
        if (threadIdx.x < st) {
            rs[threadIdx.x]  += rs[threadIdx.x + st];
            rss[threadIdx.x] += rss[threadIdx.x + st];
        }
        __syncthreads();
    }
    if (threadIdx.x == 0) {
        float mu  = rs[0] / (float)cnt;
        float var = rss[0] / (float)cnt - mu * mu;
        stats[bg * 2]     = mu;
        stats[bg * 2 + 1] = rsqrtf(var + 1e-5f);
    }
}

__global__ __launch_bounds__(256)
void gn_apply(const float* __restrict__ src, long s_bs,
              float* __restrict__ dst, long d_bs,
              const float* __restrict__ res, long r_bs,
              const float* __restrict__ w, const float* __restrict__ bb,
              const float* __restrict__ stats,
              int C, int cpg, int L, int act)
{
    const long total4 = (long)BB * C * L / 4;
    const int G = C / cpg;
    for (long i4 = (long)blockIdx.x * 256 + threadIdx.x; i4 < total4;
         i4 += (long)gridDim.x * 256) {
        long flat = i4 * 4;
        int b = (int)(flat / ((long)C * L));
        long rem = flat - (long)b * C * L;
        int c = (int)(rem / L);
        long li = rem - (long)c * L;
        int sidx = (b * G + c / cpg) * 2;
        float mu = stats[sidx], rsig = stats[sidx + 1];
        float sc = rsig * w[c];
        float sh = bb[c] - mu * sc;
        float4 vv = *reinterpret_cast<const float4*>(src + (long)b * s_bs + (long)c * L + li);
        float4 ov;
        ov.x = actf(vv.x * sc + sh, act);
        ov.y = actf(vv.y * sc + sh, act);
        ov.z = actf(vv.z * sc + sh, act);
        ov.w = actf(vv.w * sc + sh, act);
        if (res) {
            float4 rv = *reinterpret_cast<const float4*>(res + (long)b * r_bs + (long)c * L + li);
            ov.x += rv.x; ov.y += rv.y; ov.z += rv.z; ov.w += rv.w;
        }
        *reinterpret_cast<float4*>(dst + (long)b * d_bs + (long)c * L + li) = ov;
    }
}

// ---------------------------------------------------------------------------
// Transpose+convert (unchanged)
// ---------------------------------------------------------------------------
__global__ __launch_bounds__(256)
void tcvt(const float* __restrict__ in, ushort* __restrict__ out, int L)
{
    __shared__ float ls[64][65];
    const int t = threadIdx.x, b = blockIdx.y;
    const int l0 = blockIdx.x * 64;
#pragma unroll
    for (int i = 0; i < 16; ++i) {
        int f = i * 256 + t;
        int d = f >> 6, l = f & 63;
        ls[d][l] = in[(long)b * 64 * L + (long)d * L + l0 + l];
    }
    __syncthreads();
#pragma unroll
    for (int i = 0; i < 16; ++i) {
        int f = i * 256 + t;
        int l = f >> 6, d = f & 63;
        out[((long)b * L + l0 + l) * 64 + d] = f2bf(ls[d][l]);
    }
}

// ---------------------------------------------------------------------------
// MFMA attention phase 0: same geometry/reductions as round 12, with K-frag
// loads BATCHED in groups of 4 i-tiles (8 loads in flight vs 1).
// ---------------------------------------------------------------------------
__global__ __launch_bounds__(256)
void attn_stats_mfma(const ushort* __restrict__ qt, const ushort* __restrict__ kt,
                     float* __restrict__ rowmax, float* __restrict__ rowinv,
                     float* __restrict__ csp)
{
    __shared__ float red[16][5];
    __shared__ float rs_mx[16], rs_inv[16];

    const int t  = threadIdx.x;
    const int b  = blockIdx.y;
    const int n0 = blockIdx.x * 16;
    const int w  = t >> 6;
    const int ln = t & 15;
    const int lq = (t >> 4) & 3;

    const ushort* qtb = qt + ((long)b * NN + n0) * 64;
    const ushort* ktb = kt + (long)b * MM * 64;

    bf16x8 aq[2];
#pragma unroll
    for (int ks = 0; ks < 2; ++ks)
        aq[ks] = *reinterpret_cast<const bf16x8*>(qtb + (long)ln * 64 + ks * 32 + lq * 8);

    f32x4 sc[16];
#pragma unroll
    for (int ib = 0; ib < 4; ++ib) {
        bf16x8 bk[4][2];
#pragma unroll
        for (int ii = 0; ii < 4; ++ii) {
            const int m0 = (w * 16 + ib * 4 + ii) * 16;
#pragma unroll
            for (int ks = 0; ks < 2; ++ks)
                bk[ii][ks] = *reinterpret_cast<const bf16x8*>(
                    ktb + (long)(m0 + ln) * 64 + ks * 32 + lq * 8);
        }
#pragma unroll
        for (int ii = 0; ii < 4; ++ii) {
            f32x4 acc = {0.f, 0.f, 0.f, 0.f};
            acc = __builtin_amdgcn_mfma_f32_16x16x32_bf16(aq[0], bk[ii][0], acc, 0, 0, 0);
            acc = __builtin_amdgcn_mfma_f32_16x16x32_bf16(aq[1], bk[ii][1], acc, 0, 0, 0);
            sc[ib * 4 + ii] = acc;
        }
    }

    float m4[4];
#pragma unroll
    for (int r = 0; r < 4; ++r) {
        float mx = sc[0][r];
#pragma unroll
        for (int i = 1; i < 16; ++i) mx = fmaxf(mx, sc[i][r]);
#pragma unroll
        for (int off = 1; off <= 8; off <<= 1) mx = fmaxf(mx, __shfl_xor(mx, off, 64));
        m4[r] = mx;
    }
    if (ln == 0)
#pragma unroll
        for (int r = 0; r < 4; ++r) red[lq * 4 + r][w] = m4[r];
    __syncthreads();
    if (t < 16) {
        float mx = fmaxf(fmaxf(red[t][0], red[t][1]), fmaxf(red[t][2], red[t][3]));
        rs_mx[t] = mx;
        rowmax[(long)b * NN + n0 + t] = mx;
    }
    __syncthreads();

    float mxr[4], s4[4];
#pragma unroll
    for (int r = 0; r < 4; ++r) { mxr[r] = rs_mx[lq * 4 + r]; s4[r] = 0.f; }
#pragma unroll
    for (int i = 0; i < 16; ++i)
#pragma unroll
        for (int r = 0; r < 4; ++r) {
            float e = __expf(sc[i][r] - mxr[r]);
            sc[i][r] = e;
            s4[r] += e;
        }
#pragma unroll
    for (int r = 0; r < 4; ++r)
#pragma unroll
        for (int off = 1; off <= 8; off <<= 1) s4[r] += __shfl_xor(s4[r], off, 64);
    if (ln == 0)
#pragma unroll
        for (int r = 0; r < 4; ++r) red[lq * 4 + r][w] = s4[r];
    __syncthreads();
    if (t < 16) {
        float es = red[t][0] + red[t][1] + red[t][2] + red[t][3];
        float inv = 1.0f / es;
        rs_inv[t] = inv;
        rowinv[(long)b * NN + n0 + t] = inv;
    }
    __syncthreads();

    float riv[4];
#pragma unroll
    for (int r = 0; r < 4; ++r) riv[r] = rs_inv[lq * 4 + r];
    const long cbase = ((long)b * (NN / 16) + blockIdx.x) * MM;
#pragma unroll
    for (int i = 0; i < 16; ++i) {
        float c = sc[i][0] * riv[0] + sc[i][1] * riv[1] + sc[i][2] * riv[2] + sc[i][3] * riv[3];
        c += __shfl_xor(c, 16, 64);
        c += __shfl_xor(c, 32, 64);
        if (lq == 0) csp[cbase + (w * 16 + i) * 16 + ln] = c;
    }
}

// ---------------------------------------------------------------------------
// MFMA attention phase 1 v2: block = 32 q-rows, chunked QK^T->PV interleave.
// Per 256-m chunk: batched K loads (16 in flight) -> 16 QK^T MFMAs -> P chunk
// into double-buffered LDS (one sync/chunk) -> PV (8 av loads : 16 MFMAs).
// Wave roles: QK^T (rt=w&1 row-tile, ms=w>>1 m-subtile); PV (d-strip w*16).
// ---------------------------------------------------------------------------
__global__ __launch_bounds__(256)
void attn_pv_mfma(const ushort* __restrict__ qt, const ushort* __restrict__ kt,
                  const ushort* __restrict__ vb,
                  const float* __restrict__ rowmax, const float* __restrict__ rowinv,
                  const float* __restrict__ qg, float* __restrict__ ug)
{
    __shared__ ushort Pb[2][32 * 256];   // 32 KB double-buffered P chunks

    const int t  = threadIdx.x;
    const int b  = blockIdx.y;
    const int n0 = blockIdx.x * 32;
    const int w  = t >> 6;
    const int rt = w & 1;          // QK^T row-tile (rows rt*16..+16)
    const int ms = w >> 1;         // QK^T m-subtile (128 wide)
    const int ln = t & 15;
    const int lq = (t >> 4) & 3;
    const int d0 = w * 16;         // PV d-strip

    const ushort* qtb = qt + ((long)b * NN + n0 + rt * 16) * 64;
    const ushort* ktb = kt + (long)b * MM * 64;
    const ushort* vbb = vb + (long)b * 64 * MM;

    float mx[4], ri[4];
#pragma unroll
    for (int r = 0; r < 4; ++r) {
        mx[r] = rowmax[(long)b * NN + n0 + rt * 16 + lq * 4 + r];
        ri[r] = rowinv[(long)b * NN + n0 + rt * 16 + lq * 4 + r];
    }

    bf16x8 aq[2];
#pragma unroll
    for (int ks = 0; ks < 2; ++ks)
        aq[ks] = *reinterpret_cast<const bf16x8*>(qtb + (long)ln * 64 + ks * 32 + lq * 8);

    f32x4 acc2[2];
    acc2[0] = (f32x4){0.f, 0.f, 0.f, 0.f};
    acc2[1] = (f32x4){0.f, 0.f, 0.f, 0.f};

    const int swz = (ln & 7) << 3;   // read-side swizzle (n&7 == ln&7)

    for (int c = 0; c < 4; ++c) {
        // --- batched K-fragment loads for this chunk (16 in flight) ---
        bf16x8 bk[8][2];
#pragma unroll
        for (int it = 0; it < 8; ++it) {
            const int m = c * 256 + ms * 128 + it * 16 + ln;
#pragma unroll
            for (int ks = 0; ks < 2; ++ks)
                bk[it][ks] = *reinterpret_cast<const bf16x8*>(
                    ktb + (long)m * 64 + ks * 32 + lq * 8);
        }
        // --- QK^T + P-chunk write ---
        ushort* pc = &Pb[c & 1][0];
#pragma unroll
        for (int it = 0; it < 8; ++it) {
            f32x4 acc = {0.f, 0.f, 0.f, 0.f};
            acc = __builtin_amdgcn_mfma_f32_16x16x32_bf16(aq[0], bk[it][0], acc, 0, 0, 0);
            acc = __builtin_amdgcn_mfma_f32_16x16x32_bf16(aq[1], bk[it][1], acc, 0, 0, 0);
            const int mc = ms * 128 + it * 16 + ln;
#pragma unroll
            for (int r = 0; r < 4; ++r) {
                const int n = rt * 16 + lq * 4 + r;
                float p = __expf(acc[r] - mx[r]) * ri[r];
                pc[n * 256 + (mc ^ ((n & 7) << 3))] = f2bf(p);
            }
        }
        __syncthreads();
        // --- PV over this chunk (av reused across both n-tiles) ---
#pragma unroll
        for (int ks = 0; ks < 8; ++ks) {
            bf16x8 av = *reinterpret_cast<const bf16x8*>(
                vbb + (long)(d0 + ln) * MM + c * 256 + ks * 32 + lq * 8);
            const int mo = ks * 32 + lq * 8;
#pragma unroll
            for (int nt = 0; nt < 2; ++nt) {
                bf16x8 bp = *reinterpret_cast<const bf16x8*>(
                    &pc[(nt * 16 + ln) * 256 + (mo ^ swz)]);
                acc2[nt] = __builtin_amdgcn_mfma_f32_16x16x32_bf16(av, bp, acc2[nt], 0, 0, 0);
            }
        }
        // no trailing sync: next chunk writes the other Pb buffer
    }

    const long qb = (long)b * 64 * NN;
#pragma unroll
    for (int nt = 0; nt < 2; ++nt)
#pragma unroll
        for (int r = 0; r < 4; ++r) {
            const int dd = d0 + lq * 4 + r;
            const long idx = qb + (long)dd * NN + n0 + nt * 16 + ln;
            ug[idx] = qg[idx] - acc2[nt][r];
        }
}

__global__ __launch_bounds__(256)
void colsum_reduce(const float* __restrict__ csp, float* __restrict__ cs, int NT)
{
    int idx = blockIdx.x * 256 + threadIdx.x;   // over B*M
    int b = idx / MM, m = idx - b * MM;
    const float* p = csp + (long)b * NT * MM + m;
    float s = 0.f;
    for (int i = 0; i < NT; ++i) s += p[(long)i * MM];
    cs[idx] = s;
}

__global__ __launch_bounds__(256)
void vscale_cvt(const float* __restrict__ v, const float* __restrict__ cs,
                ushort* __restrict__ vb)
{
    long i4 = (long)blockIdx.x * 256 + threadIdx.x;
    long flat = i4 * 4;                          // index into [B][64][M]
    int b = (int)(flat / (64L * MM));
    int m = (int)(flat % MM);
    float4 vv = *reinterpret_cast<const float4*>(v + flat);
    float4 cv = *reinterpret_cast<const float4*>(cs + (long)b * MM + m);
    ushort4 o;
    o.x = f2bf(vv.x / (1e-9f + cv.x));
    o.y = f2bf(vv.y / (1e-9f + cv.y));
    o.z = f2bf(vv.z / (1e-9f + cv.z));
    o.w = f2bf(vv.w / (1e-9f + cv.w));
    *reinterpret_cast<ushort4*>(vb + flat) = o;
}

// ---------------------------------------------------------------------------
// Final GN4 + relu + transpose (unchanged)
// ---------------------------------------------------------------------------
__global__ __launch_bounds__(256)
void gn_out_transpose(const float* __restrict__ s2,
                      const float* __restrict__ w, const float* __restrict__ bb,
                      const float* __restrict__ stats,
                      float* __restrict__ out)
{
    __shared__ float ls[128 * 65];
    const int t = threadIdx.x;
    const int b = blockIdx.y;
    const int n0 = blockIdx.x * 64;
#pragma unroll
    for (int i = 0; i < 8; ++i) {
        int f4 = i * 256 + t;
        int o = f4 >> 4, c4 = f4 & 15;
        float4 vv = *reinterpret_cast<const float4*>(
            s2 + (long)b * 128 * NN + (long)o * NN + n0 + c4 * 4);
        int sidx = (b * 4 + (o >> 5)) * 2;
        float mu = stats[sidx], rsig = stats[sidx + 1];
        float sc = rsig * w[o], sh = bb[o] - mu * sc;
        ls[o * 65 + c4 * 4 + 0] = fmaxf(vv.x * sc + sh, 0.f);
        ls[o * 65 + c4 * 4 + 1] = fmaxf(vv.y * sc + sh, 0.f);
        ls[o * 65 + c4 * 4 + 2] = fmaxf(vv.z * sc + sh, 0.f);
        ls[o * 65 + c4 * 4 + 3] = fmaxf(vv.w * sc + sh, 0.f);
    }
    __syncthreads();
#pragma unroll
    for (int i = 0; i < 8; ++i) {
        int f4 = i * 256 + t;
        int nn = f4 >> 5, o4 = f4 & 31;
        float4 ov;
        ov.x = ls[(o4 * 4 + 0) * 65 + nn];
        ov.y = ls[(o4 * 4 + 1) * 65 + nn];
        ov.z = ls[(o4 * 4 + 2) * 65 + nn];
        ov.w = ls[(o4 * 4 + 3) * 65 + nn];
        *reinterpret_cast<float4*>(out + (long)b * NN * 128 + (long)(n0 + nn) * 128 + o4 * 4) = ov;
    }
}

} // namespace

extern "C" void kernel_launch(void* const* d_in, const int* in_sizes, int n_in,
                              void* d_out, int out_size, void* d_ws, size_t ws_size,
                              hipStream_t stream)
{
    (void)in_sizes; (void)n_in; (void)out_size; (void)ws_size;

    const float* x         = (const float*)d_in[0];
    const float* x_global  = (const float*)d_in[1];
    const float* xyz       = (const float*)d_in[2];
    const float* xyz_g     = (const float*)d_in[3];
    const float* conv1_w   = (const float*)d_in[4];
    const float* gn1_w     = (const float*)d_in[5];
    const float* gn1_b     = (const float*)d_in[6];
    const float* conv2_w   = (const float*)d_in[7];
    const float* gn2_w     = (const float*)d_in[8];
    const float* gn2_b     = (const float*)d_in[9];
    const float* sa_qk_w   = (const float*)d_in[10];
    const float* sa_v_w    = (const float*)d_in[11];
    const float* sa_v_b    = (const float*)d_in[12];
    const float* sa_t_w    = (const float*)d_in[13];
    const float* sa_t_b    = (const float*)d_in[14];
    const float* sa_gn_w   = (const float*)d_in[15];
    const float* sa_gn_b   = (const float*)d_in[16];
    const float* sa_pos_w  = (const float*)d_in[17];
    const float* sa_posG_w = (const float*)d_in[18];
    const float* fuse_w    = (const float*)d_in[19];
    const float* fuse_gn_w = (const float*)d_in[20];
    const float* fuse_gn_b = (const float*)d_in[21];
    const float* convs1_w  = (const float*)d_in[22];
    const float* convs1_b  = (const float*)d_in[23];
    const float* gns1_w    = (const float*)d_in[24];
    const float* gns1_b    = (const float*)d_in[25];
    const float* convs2_w  = (const float*)d_in[26];
    const float* convs2_b  = (const float*)d_in[27];
    const float* gns2_w    = (const float*)d_in[28];
    const float* gns2_b    = (const float*)d_in[29];

    // ---- workspace layout; identical to round 12 (proven) ----
    constexpr long SZ_BN  = (long)BB * 64 * NN;
    constexpr long SZ_BM  = (long)BB * 64 * MM;
    constexpr long SZ_CSP = (long)BB * (NN / 16) * MM;

    float* ws = (float*)d_ws;
    long o = 0;
    float* p_h   = ws + o; o += SZ_BN;
    float* p_hg  = ws + o; o += SZ_BM;
    float* p_q   = ws + o; o += SZ_BN;
    float* p_k   = ws + o; o += SZ_BM;
    float* p_v   = ws + o; o += SZ_BM;
    float* p_u   = ws + o; o += SZ_BN;
    float* p_csp = ws + o; o += SZ_CSP;
    float* p_cs  = ws + o; o += (long)BB * MM;
    float* p_xc  = ws + o; o += (long)BB * 256 * NN;
    float* p_xf  = ws + o; o += (long)BB * 128 * NN;
    float* p_st  = ws + o; o += 4096;
    float* p_rmx = ws + o; o += (long)BB * NN;
    float* p_rin = ws + o; o += (long)BB * NN;
    float* p_s1  = ws;
    float* p_s2  = p_xf;
    ushort* p_qt = (ushort*)p_xf;
    ushort* p_kt = (ushort*)(p_xf + 2097152);
    ushort* p_vb = (ushort*)(p_xf + 2097152 + 524288);

    // h = relu(GN16(conv1(x)))   (C=6 -> old kernel)
    conv_gemm<<<dim3(NN / 128, 1, BB), 256, 0, stream>>>(
        x, 6, 6L * NN, conv1_w, nullptr, 0, 0, nullptr, nullptr, p_h, 64L * NN, NN);
    gn_stats<<<BB * 16, 256, 0, stream>>>(p_h, 64L * NN, 4, NN, 16, p_st);
    gn_apply<<<2048, 256, 0, stream>>>(p_h, 64L * NN, p_h, 64L * NN, nullptr, 0,
                                       gn1_w, gn1_b, p_st, 64, 4, NN, 1);
    // hg = relu(GN16(conv2(x_global)))   (C=32 -> MFMA)
    conv_mfma<<<dim3(MM / 128, 1, BB), 256, 0, stream>>>(
        x_global, 32, 32L * MM, conv2_w, nullptr, 0, nullptr, nullptr, p_hg, 64L * MM, MM);
    gn_stats<<<BB * 16, 256, 0, stream>>>(p_hg, 64L * MM, 4, MM, 16, p_st);
    gn_apply<<<2048, 256, 0, stream>>>(p_hg, 64L * MM, p_hg, 64L * MM, nullptr, 0,
                                       gn2_w, gn2_b, p_st, 64, 4, MM, 1);

    const float* cur = p_h;
    long cur_bs = 64L * NN;
    for (int i = 0; i < 4; ++i) {
        // q = qk_w*cur + pos_w*xyz
        conv_mfma<<<dim3(NN / 128, 1, BB), 256, 0, stream>>>(
            cur, 64, cur_bs, sa_qk_w + i * 4096,
            xyz, 3L * NN, sa_pos_w + i * 192, nullptr, p_q, 64L * NN, NN);
        tcvt<<<dim3(NN / 64, BB), 256, 0, stream>>>(p_q, p_qt, NN);
        // k = qk_w*hg + posG_w*xyz_g
        conv_mfma<<<dim3(MM / 128, 1, BB), 256, 0, stream>>>(
            p_hg, 64, 64L * MM, sa_qk_w + i * 4096,
            xyz_g, 3L * MM, sa_posG_w + i * 192, nullptr, p_k, 64L * MM, MM);
        tcvt<<<dim3(MM / 64, BB), 256, 0, stream>>>(p_k, p_kt, MM);
        // v = v_w*hg + posG_w*xyz_g + v_b
        conv_mfma<<<dim3(MM / 128, 1, BB), 256, 0, stream>>>(
            p_hg, 64, 64L * MM, sa_v_w + i * 4096,
            xyz_g, 3L * MM, sa_posG_w + i * 192, sa_v_b + i * 64, p_v, 64L * MM, MM);
        // phase 0: MFMA softmax stats + column partials
        attn_stats_mfma<<<dim3(NN / 16, BB), 256, 0, stream>>>(p_qt, p_kt, p_rmx, p_rin, p_csp);
        colsum_reduce<<<BB * MM / 256, 256, 0, stream>>>(p_csp, p_cs, NN / 16);
        vscale_cvt<<<BB * 64 * MM / 1024, 256, 0, stream>>>(p_v, p_cs, p_vb);
        // phase 1: u = q - P*v'  (32-row blocks, chunked QK^T->PV)
        attn_pv_mfma<<<dim3(NN / 32, BB), 256, 0, stream>>>(
            p_qt, p_kt, p_vb, p_rmx, p_rin, p_q, p_u);
        // t = t_w*u + t_b
        conv_mfma<<<dim3(NN / 128, 1, BB), 256, 0, stream>>>(
            p_u, 64, 64L * NN, sa_t_w + i * 4096,
            nullptr, 0, nullptr, sa_t_b + i * 64, p_h, 64L * NN, NN);
        // out_i = q + relu(GN4(t))  -> xc slice i
        gn_stats<<<BB * 4, 256, 0, stream>>>(p_h, 64L * NN, 16, NN, 4, p_st);
        gn_apply<<<2048, 256, 0, stream>>>(p_h, 64L * NN,
                                           p_xc + (long)i * 64 * NN, 256L * NN,
                                           p_q, 64L * NN,
                                           sa_gn_w + i * 64, sa_gn_b + i * 64, p_st,
                                           64, 16, NN, 1);
        cur = p_xc + (long)i * 64 * NN;
        cur_bs = 256L * NN;
    }

    // xf = leaky(GN16(fuse_w * xc))
    conv_mfma<<<dim3(NN / 128, 2, BB), 256, 0, stream>>>(
        p_xc, 256, 256L * NN, fuse_w, nullptr, 0, nullptr, nullptr, p_xf, 128L * NN, NN);
    gn_stats<<<BB * 16, 256, 0, stream>>>(p_xf, 128L * NN, 8, NN, 16, p_st);
    gn_apply<<<2048, 256, 0, stream>>>(p_xf, 128L * NN, p_xf, 128L * NN, nullptr, 0,
                                       fuse_gn_w, fuse_gn_b, p_st, 128, 8, NN, 2);
    // s1 = relu(GN8(convs1_w * xf + b))
    conv_mfma<<<dim3(NN / 128, 8, BB), 256, 0, stream>>>(
        p_xf, 128, 128L * NN, convs1_w, nullptr, 0, nullptr, convs1_b, p_s1, 512L * NN, NN);
    gn_stats<<<BB * 8, 256, 0, stream>>>(p_s1, 512L * NN, 64, NN, 8, p_st);
    gn_apply<<<2048, 256, 0, stream>>>(p_s1, 512L * NN, p_s1, 512L * NN, nullptr, 0,
                                       gns1_w, gns1_b, p_st, 512, 64, NN, 1);
    // s2 = GN4(convs2_w * s1 + b), relu fused into transpose
    conv_mfma<<<dim3(NN / 128, 2, BB), 256, 0, stream>>>(
        p_s1, 512, 512L * NN, convs2_w, nullptr, 0, nullptr, convs2_b, p_s2, 128L * NN, NN);
    gn_stats<<<BB * 4, 256, 0, stream>>>(p_s2, 128L * NN, 32, NN, 4, p_st);
    gn_out_transpose<<<dim3(NN / 64, BB), 256, 0, stream>>>(
        p_s2, gns2_w, gns2_b, p_st, (float*)d_out);
}

// Round 14
// 1581.061 us; speedup vs baseline: 4.7002x; 1.0006x over previous
//
#include <hip/hip_runtime.h>
#include <hip/hip_bf16.h>

namespace {

constexpr int BB = 16;
constexpr int NN = 4096;
constexpr int MM = 1024;

using f32x4  = __attribute__((ext_vector_type(4))) float;
using bf16x8 = __attribute__((ext_vector_type(8))) short;

__device__ __forceinline__ float actf(float x, int act) {
    if (act == 1) return fmaxf(x, 0.f);
    if (act == 2) return x >= 0.f ? x : 0.2f * x;
    return x;
}

__device__ __forceinline__ ushort f2bf(float x) {
    __hip_bfloat16 h = __float2bfloat16(x);
    return *reinterpret_cast<ushort*>(&h);
}

// pack x as (hi_bf16 | lo_bf16<<16); x == hi + lo to ~2^-18 relative
__device__ __forceinline__ uint hilo_pack(float x) {
    ushort h = f2bf(x);
    float hf = __uint_as_float(((uint)h) << 16);
    ushort l = f2bf(x - hf);
    return (uint)h | ((uint)l << 16);
}

// 8 packed dwords -> hi bf16x8, lo bf16x8
__device__ __forceinline__ void split8(const uint* d, bf16x8& hi, bf16x8& lo) {
    union { uint u[4]; bf16x8 v; } H, L;
#pragma unroll
    for (int j = 0; j < 4; ++j) {
        H.u[j] = (d[2 * j] & 0xffffu) | (d[2 * j + 1] << 16);
        L.u[j] = (d[2 * j] >> 16) | (d[2 * j + 1] & 0xffff0000u);
    }
    hi = H.v; lo = L.v;
}

// ---------------------------------------------------------------------------
// MFMA pointwise-conv, split-precision bf16 (unchanged from round 12)
// ---------------------------------------------------------------------------
__global__ __launch_bounds__(256)
void conv_mfma(const float* __restrict__ X, int C, long x_bs,
               const float* __restrict__ W,
               const float* __restrict__ X2, long x2_bs,
               const float* __restrict__ W2,
               const float* __restrict__ bias,
               float* __restrict__ Y, long y_bs, int L)
{
    __shared__ uint Wp[64 * 33];
    __shared__ uint Xp[128 * 33];
    const int t  = threadIdx.x;
    const int b  = blockIdx.z;
    const int o0 = blockIdx.y * 64;
    const int l0 = blockIdx.x * 128;
    const int w  = t >> 6;
    const int ln = t & 15;
    const int lq = (t >> 4) & 3;
    const int wo = (w & 1) * 32;
    const int wl = (w >> 1) * 64;
    const int sl  = t & 127;
    const int sch = (t >> 7) * 16;

    f32x4 acc[2][4];
#pragma unroll
    for (int i = 0; i < 2; ++i)
#pragma unroll
        for (int j = 0; j < 4; ++j) acc[i][j] = (f32x4){0.f, 0.f, 0.f, 0.f};

    for (int c0 = 0; c0 < C; c0 += 32) {
        __syncthreads();
#pragma unroll
        for (int i = 0; i < 2; ++i) {
            int f = i * 256 + t;
            int r = f >> 3, q4 = (f & 7) * 4;
            float4 wv = *reinterpret_cast<const float4*>(&W[(long)(o0 + r) * C + c0 + q4]);
            Wp[r * 33 + q4 + 0] = hilo_pack(wv.x);
            Wp[r * 33 + q4 + 1] = hilo_pack(wv.y);
            Wp[r * 33 + q4 + 2] = hilo_pack(wv.z);
            Wp[r * 33 + q4 + 3] = hilo_pack(wv.w);
        }
        {
            const float* xc = X + (long)b * x_bs + (long)(c0 + sch) * L + l0 + sl;
            uint tmp[16];
#pragma unroll
            for (int c = 0; c < 16; ++c) tmp[c] = hilo_pack(xc[(long)c * L]);
#pragma unroll
            for (int c4 = 0; c4 < 4; ++c4) {
                uint4 v = make_uint4(tmp[c4 * 4], tmp[c4 * 4 + 1],
                                     tmp[c4 * 4 + 2], tmp[c4 * 4 + 3]);
                *reinterpret_cast<uint4*>(&Xp[sl * 33 + sch + c4 * 4]) = v;
            }
        }
        __syncthreads();

        bf16x8 ahi[2], alo[2];
#pragma unroll
        for (int ot = 0; ot < 2; ++ot) {
            uint d[8];
            *reinterpret_cast<uint4*>(d) =
                *reinterpret_cast<const uint4*>(&Wp[(wo + ot * 16 + ln) * 33 + lq * 8]);
            *reinterpret_cast<uint4*>(d + 4) =
                *reinterpret_cast<const uint4*>(&Wp[(wo + ot * 16 + ln) * 33 + lq * 8 + 4]);
            split8(d, ahi[ot], alo[ot]);
        }
#pragma unroll
        for (int lt = 0; lt < 4; ++lt) {
            uint d[8];
            *reinterpret_cast<uint4*>(d) =
                *reinterpret_cast<const uint4*>(&Xp[(wl + lt * 16 + ln) * 33 + lq * 8]);
            *reinterpret_cast<uint4*>(d + 4) =
                *reinterpret_cast<const uint4*>(&Xp[(wl + lt * 16 + ln) * 33 + lq * 8 + 4]);
            bf16x8 bhi, blo;
            split8(d, bhi, blo);
#pragma unroll
            for (int ot = 0; ot < 2; ++ot) {
                acc[ot][lt] = __builtin_amdgcn_mfma_f32_16x16x32_bf16(alo[ot], bhi, acc[ot][lt], 0, 0, 0);
                acc[ot][lt] = __builtin_amdgcn_mfma_f32_16x16x32_bf16(ahi[ot], blo, acc[ot][lt], 0, 0, 0);
                acc[ot][lt] = __builtin_amdgcn_mfma_f32_16x16x32_bf16(ahi[ot], bhi, acc[ot][lt], 0, 0, 0);
            }
        }
    }

    float x2v[4][3];
    if (X2) {
#pragma unroll
        for (int lt = 0; lt < 4; ++lt) {
            const int l = l0 + wl + lt * 16 + ln;
#pragma unroll
            for (int c = 0; c < 3; ++c)
                x2v[lt][c] = X2[(long)b * x2_bs + (long)c * L + l];
        }
    }
#pragma unroll
    for (int ot = 0; ot < 2; ++ot)
#pragma unroll
        for (int r = 0; r < 4; ++r) {
            const int o = o0 + wo + ot * 16 + lq * 4 + r;
            float base = bias ? bias[o] : 0.f;
            float w20 = 0.f, w21 = 0.f, w22 = 0.f;
            if (X2) {
                w20 = W2[o * 3 + 0];
                w21 = W2[o * 3 + 1];
                w22 = W2[o * 3 + 2];
            }
#pragma unroll
            for (int lt = 0; lt < 4; ++lt) {
                const int l = l0 + wl + lt * 16 + ln;
                float val = acc[ot][lt][r] + base;
                if (X2)
                    val += w20 * x2v[lt][0] + w21 * x2v[lt][1] + w22 * x2v[lt][2];
                Y[(long)b * y_bs + (long)o * L + l] = val;
            }
        }
}

// ---------------------------------------------------------------------------
// Old fp32 conv (kept only for conv1, C=6)
// ---------------------------------------------------------------------------
__global__ __launch_bounds__(256)
void conv_gemm(const float* __restrict__ X1, int C1, long x1_bs,
               const float* __restrict__ W1,
               const float* __restrict__ X2, int C2, long x2_bs,
               const float* __restrict__ W2,
               const float* __restrict__ bias,
               float* __restrict__ Y, long y_bs, int L)
{
    __shared__ float Wt[64][17];
    __shared__ float Xt[16][128];
    const int t  = threadIdx.x;
    const int b  = blockIdx.z;
    const int o0 = blockIdx.y * 64;
    const int l0 = blockIdx.x * 128;
    const int ty = t >> 4, tx = t & 15;

    float acc[4][8];
#pragma unroll
    for (int i = 0; i < 4; ++i)
#pragma unroll
        for (int j = 0; j < 8; ++j) acc[i][j] = 0.f;

    for (int pass = 0; pass < 2; ++pass) {
        const float* X = pass ? X2 : X1;
        const float* W = pass ? W2 : W1;
        const int    C = pass ? C2 : C1;
        const long xbs = pass ? x2_bs : x1_bs;
        if (C <= 0 || X == nullptr) continue;
        for (int c0 = 0; c0 < C; c0 += 16) {
            __syncthreads();
#pragma unroll
            for (int i = 0; i < 4; ++i) {
                int flat = i * 256 + t;
                int oo = flat >> 4, kk = flat & 15;
                Wt[oo][kk] = (c0 + kk < C) ? W[(long)(o0 + oo) * C + c0 + kk] : 0.f;
            }
#pragma unroll
            for (int i = 0; i < 2; ++i) {
                int f4 = i * 256 + t;
                int kk = f4 >> 5, c4 = f4 & 31;
                float4 xv = make_float4(0.f, 0.f, 0.f, 0.f);
                if (c0 + kk < C)
                    xv = *reinterpret_cast<const float4*>(
                        X + (long)b * xbs + (long)(c0 + kk) * L + l0 + c4 * 4);
                *reinterpret_cast<float4*>(&Xt[kk][c4 * 4]) = xv;
            }
            __syncthreads();
#pragma unroll
            for (int kk = 0; kk < 16; ++kk) {
                float wv[4];
#pragma unroll
                for (int i = 0; i < 4; ++i) wv[i] = Wt[ty * 4 + i][kk];
                float4 xa = *reinterpret_cast<const float4*>(&Xt[kk][tx * 8]);
                float4 xb = *reinterpret_cast<const float4*>(&Xt[kk][tx * 8 + 4]);
                float xv[8] = {xa.x, xa.y, xa.z, xa.w, xb.x, xb.y, xb.z, xb.w};
#pragma unroll
                for (int i = 0; i < 4; ++i)
#pragma unroll
                    for (int j = 0; j < 8; ++j) acc[i][j] += wv[i] * xv[j];
            }
        }
    }

#pragma unroll
    for (int i = 0; i < 4; ++i) {
        const int oo = o0 + ty * 4 + i;
        const float bv = bias ? bias[oo] : 0.f;
        float* yp = Y + (long)b * y_bs + (long)oo * L + l0 + tx * 8;
        float4 v0 = make_float4(acc[i][0] + bv, acc[i][1] + bv, acc[i][2] + bv, acc[i][3] + bv);
        float4 v1 = make_float4(acc[i][4] + bv, acc[i][5] + bv, acc[i][6] + bv, acc[i][7] + bv);
        *reinterpret_cast<float4*>(yp)     = v0;
        *reinterpret_cast<float4*>(yp + 4) = v1;
    }
}

// ---------------------------------------------------------------------------
// GroupNorm stats / apply (unchanged)
// ---------------------------------------------------------------------------
__global__ __launch_bounds__(256)
void gn_stats(const float* __restrict__ Y, long y_bs, int cpg, int L, int G,
              float* __restrict__ stats)
{
    const int bg = blockIdx.x;
    const int b = bg / G, g = bg - b * G;
    const float* p = Y + (long)b * y_bs + (long)g * cpg * L;
    const long cnt = (long)cpg * L;
    float s = 0.f, ss = 0.f;
    for (long i = (long)threadIdx.x * 4; i < cnt; i += 256 * 4) {
        float4 v = *reinterpret_cast<const float4*>(p + i);
        s  += v.x + v.y + v.z + v.w;
        ss += v.x * v.x + v.y * v.y + v.z * v.z + v.w * v.w;
    }
    __shared__ float rs[256], rss[256];
    rs[threadIdx.x] = s; rss[threadIdx.x] = ss;
    __syncthreads();
    for (int st = 128; st > 0; st >>= 1) {
        if (threadIdx.x < st) {
            rs[threadIdx.x]  += rs[threadIdx.x + st];
            rss[threadIdx.x] += rss[threadIdx.x + st];
        }
        __syncthreads();
    }
    if (threadIdx.x == 0) {
        float mu  = rs[0] / (float)cnt;
        float var = rss[0] / (float)cnt - mu * mu;
        stats[bg * 2]     = mu;
        stats[bg * 2 + 1] = rsqrtf(var + 1e-5f);
    }
}

__global__ __launch_bounds__(256)
void gn_apply(const float* __restrict__ src, long s_bs,
              float* __restrict__ dst, long d_bs,
              const float* __restrict__ res, long r_bs,
              const float* __restrict__ w, const float* __restrict__ bb,
              const float* __restrict__ stats,
              int C, int cpg, int L, int act)
{
    const long total4 = (long)BB * C * L / 4;
    const int G = C / cpg;
    for (long i4 = (long)blockIdx.x * 256 + threadIdx.x; i4 < total4;
         i4 += (long)gridDim.x * 256) {
        long flat = i4 * 4;
        int b = (int)(flat / ((long)C * L));
        long rem = flat - (long)b * C * L;
        int c = (int)(rem / L);
        long li = rem - (long)c * L;
        int sidx = (b * G + c / cpg) * 2;
        float mu = stats[sidx], rsig = stats[sidx + 1];
        float sc = rsig * w[c];
        float sh = bb[c] - mu * sc;
        float4 vv = *reinterpret_cast<const float4*>(src + (long)b * s_bs + (long)c * L + li);
        float4 ov;
        ov.x = actf(vv.x * sc + sh, act);
        ov.y = actf(vv.y * sc + sh, act);
        ov.z = actf(vv.z * sc + sh, act);
        ov.w = actf(vv.w * sc + sh, act);
        if (res) {
            float4 rv = *reinterpret_cast<const float4*>(res + (long)b * r_bs + (long)c * L + li);
            ov.x += rv.x; ov.y += rv.y; ov.z += rv.z; ov.w += rv.w;
        }
        *reinterpret_cast<float4*>(dst + (long)b * d_bs + (long)c * L + li) = ov;
    }
}

// ---------------------------------------------------------------------------
// Transpose+convert (unchanged)
// ---------------------------------------------------------------------------
__global__ __launch_bounds__(256)
void tcvt(const float* __restrict__ in, ushort* __restrict__ out, int L)
{
    __shared__ float ls[64][65];
    const int t = threadIdx.x, b = blockIdx.y;
    const int l0 = blockIdx.x * 64;
#pragma unroll
    for (int i = 0; i < 16; ++i) {
        int f = i * 256 + t;
        int d = f >> 6, l = f & 63;
        ls[d][l] = in[(long)b * 64 * L + (long)d * L + l0 + l];
    }
    __syncthreads();
#pragma unroll
    for (int i = 0; i < 16; ++i) {
        int f = i * 256 + t;
        int l = f >> 6, d = f & 63;
        out[((long)b * L + l0 + l) * 64 + d] = f2bf(ls[d][l]);
    }
}

// ---------------------------------------------------------------------------
// MFMA attention phase 0: same geometry/reductions as round 12, with K-frag
// loads BATCHED in groups of 4 i-tiles (8 loads in flight vs 1).
// ---------------------------------------------------------------------------
__global__ __launch_bounds__(256)
void attn_stats_mfma(const ushort* __restrict__ qt, const ushort* __restrict__ kt,
                     float* __restrict__ rowmax, float* __restrict__ rowinv,
                     float* __restrict__ csp)
{
    __shared__ float red[16][5];
    __shared__ float rs_mx[16], rs_inv[16];

    const int t  = threadIdx.x;
    const int b  = blockIdx.y;
    const int n0 = blockIdx.x * 16;
    const int w  = t >> 6;
    const int ln = t & 15;
    const int lq = (t >> 4) & 3;

    const ushort* qtb = qt + ((long)b * NN + n0) * 64;
    const ushort* ktb = kt + (long)b * MM * 64;

    bf16x8 aq[2];
#pragma unroll
    for (int ks = 0; ks < 2; ++ks)
        aq[ks] = *reinterpret_cast<const bf16x8*>(qtb + (long)ln * 64 + ks * 32 + lq * 8);

    f32x4 sc[16];
#pragma unroll
    for (int ib = 0; ib < 4; ++ib) {
        bf16x8 bk[4][2];
#pragma unroll
        for (int ii = 0; ii < 4; ++ii) {
            const int m0 = (w * 16 + ib * 4 + ii) * 16;
#pragma unroll
            for (int ks = 0; ks < 2; ++ks)
                bk[ii][ks] = *reinterpret_cast<const bf16x8*>(
                    ktb + (long)(m0 + ln) * 64 + ks * 32 + lq * 8);
        }
#pragma unroll
        for (int ii = 0; ii < 4; ++ii) {
            f32x4 acc = {0.f, 0.f, 0.f, 0.f};
            acc = __builtin_amdgcn_mfma_f32_16x16x32_bf16(aq[0], bk[ii][0], acc, 0, 0, 0);
            acc = __builtin_amdgcn_mfma_f32_16x16x32_bf16(aq[1], bk[ii][1], acc, 0, 0, 0);
            sc[ib * 4 + ii] = acc;
        }
    }

    float m4[4];
#pragma unroll
    for (int r = 0; r < 4; ++r) {
        float mx = sc[0][r];
#pragma unroll
        for (int i = 1; i < 16; ++i) mx = fmaxf(mx, sc[i][r]);
#pragma unroll
        for (int off = 1; off <= 8; off <<= 1) mx = fmaxf(mx, __shfl_xor(mx, off, 64));
        m4[r] = mx;
    }
    if (ln == 0)
#pragma unroll
        for (int r = 0; r < 4; ++r) red[lq * 4 + r][w] = m4[r];
    __syncthreads();
    if (t < 16) {
        float mx = fmaxf(fmaxf(red[t][0], red[t][1]), fmaxf(red[t][2], red[t][3]));
        rs_mx[t] = mx;
        rowmax[(long)b * NN + n0 + t] = mx;
    }
    __syncthreads();

    float mxr[4], s4[4];
#pragma unroll
    for (int r = 0; r < 4; ++r) { mxr[r] = rs_mx[lq * 4 + r]; s4[r] = 0.f; }
#pragma unroll
    for (int i = 0; i < 16; ++i)
#pragma unroll
        for (int r = 0; r < 4; ++r) {
            float e = __expf(sc[i][r] - mxr[r]);
            sc[i][r] = e;
            s4[r] += e;
        }
#pragma unroll
    for (int r = 0; r < 4; ++r)
#pragma unroll
        for (int off = 1; off <= 8; off <<= 1) s4[r] += __shfl_xor(s4[r], off, 64);
    if (ln == 0)
#pragma unroll
        for (int r = 0; r < 4; ++r) red[lq * 4 + r][w] = s4[r];
    __syncthreads();
    if (t < 16) {
        float es = red[t][0] + red[t][1] + red[t][2] + red[t][3];
        float inv = 1.0f / es;
        rs_inv[t] = inv;
        rowinv[(long)b * NN + n0 + t] = inv;
    }
    __syncthreads();

    float riv[4];
#pragma unroll
    for (int r = 0; r < 4; ++r) riv[r] = rs_inv[lq * 4 + r];
    const long cbase = ((long)b * (NN / 16) + blockIdx.x) * MM;
#pragma unroll
    for (int i = 0; i < 16; ++i) {
        float c = sc[i][0] * riv[0] + sc[i][1] * riv[1] + sc[i][2] * riv[2] + sc[i][3] * riv[3];
        c += __shfl_xor(c, 16, 64);
        c += __shfl_xor(c, 32, 64);
        if (lq == 0) csp[cbase + (w * 16 + i) * 16 + ln] = c;
    }
}

// ---------------------------------------------------------------------------
// MFMA attention phase 1 v2: block = 32 q-rows, chunked QK^T->PV interleave.
// Per 256-m chunk: batched K loads (16 in flight) -> 16 QK^T MFMAs -> P chunk
// into double-buffered LDS (one sync/chunk) -> PV (8 av loads : 16 MFMAs).
// Wave roles: QK^T (rt=w&1 row-tile, ms=w>>1 m-subtile); PV (d-strip w*16).
// ---------------------------------------------------------------------------
__global__ __launch_bounds__(256)
void attn_pv_mfma(const ushort* __restrict__ qt, const ushort* __restrict__ kt,
                  const ushort* __restrict__ vb,
                  const float* __restrict__ rowmax, const float* __restrict__ rowinv,
                  const float* __restrict__ qg, float* __restrict__ ug)
{
    __shared__ ushort Pb[2][32 * 256];   // 32 KB double-buffered P chunks

    const int t  = threadIdx.x;
    const int b  = blockIdx.y;
    const int n0 = blockIdx.x * 32;
    const int w  = t >> 6;
    const int rt = w & 1;          // QK^T row-tile (rows rt*16..+16)
    const int ms = w >> 1;         // QK^T m-subtile (128 wide)
    const int ln = t & 15;
    const int lq = (t >> 4) & 3;
    const int d0 = w * 16;         // PV d-strip

    const ushort* qtb = qt + ((long)b * NN + n0 + rt * 16) * 64;
    const ushort* ktb = kt + (long)b * MM * 64;
    const ushort* vbb = vb + (long)b * 64 * MM;

    float mx[4], ri[4];
#pragma unroll
    for (int r = 0; r < 4; ++r) {
        mx[r] = rowmax[(long)b * NN + n0 + rt * 16 + lq * 4 + r];
        ri[r] = rowinv[(long)b * NN + n0 + rt * 16 + lq * 4 + r];
    }

    bf16x8 aq[2];
#pragma unroll
    for (int ks = 0; ks < 2; ++ks)
        aq[ks] = *reinterpret_cast<const bf16x8*>(qtb + (long)ln * 64 + ks * 32 + lq * 8);

    f32x4 acc2[2];
    acc2[0] = (f32x4){0.f, 0.f, 0.f, 0.f};
    acc2[1] = (f32x4){0.f, 0.f, 0.f, 0.f};

    const int swz = (ln & 7) << 3;   // read-side swizzle (n&7 == ln&7)

    for (int c = 0; c < 4; ++c) {
        // --- batched K-fragment loads for this chunk (16 in flight) ---
        bf16x8 bk[8][2];
#pragma unroll
        for (int it = 0; it < 8; ++it) {
            const int m = c * 256 + ms * 128 + it * 16 + ln;
#pragma unroll
            for (int ks = 0; ks < 2; ++ks)
                bk[it][ks] = *reinterpret_cast<const bf16x8*>(
                    ktb + (long)m * 64 + ks * 32 + lq * 8);
        }
        // --- QK^T + P-chunk write ---
        ushort* pc = &Pb[c & 1][0];
#pragma unroll
        for (int it = 0; it < 8; ++it) {
            f32x4 acc = {0.f, 0.f, 0.f, 0.f};
            acc = __builtin_amdgcn_mfma_f32_16x16x32_bf16(aq[0], bk[it][0], acc, 0, 0, 0);
            acc = __builtin_amdgcn_mfma_f32_16x16x32_bf16(aq[1], bk[it][1], acc, 0, 0, 0);
            const int mc = ms * 128 + it * 16 + ln;
#pragma unroll
            for (int r = 0; r < 4; ++r) {
                const int n = rt * 16 + lq * 4 + r;
                float p = __expf(acc[r] - mx[r]) * ri[r];
                pc[n * 256 + (mc ^ ((n & 7) << 3))] = f2bf(p);
            }
        }
        __syncthreads();
        // --- PV over this chunk (av reused across both n-tiles) ---
#pragma unroll
        for (int ks = 0; ks < 8; ++ks) {
            bf16x8 av = *reinterpret_cast<const bf16x8*>(
                vbb + (long)(d0 + ln) * MM + c * 256 + ks * 32 + lq * 8);
            const int mo = ks * 32 + lq * 8;
#pragma unroll
            for (int nt = 0; nt < 2; ++nt) {
                bf16x8 bp = *reinterpret_cast<const bf16x8*>(
                    &pc[(nt * 16 + ln) * 256 + (mo ^ swz)]);
                acc2[nt] = __builtin_amdgcn_mfma_f32_16x16x32_bf16(av, bp, acc2[nt], 0, 0, 0);
            }
        }
        // no trailing sync: next chunk writes the other Pb buffer
    }

    const long qb = (long)b * 64 * NN;
#pragma unroll
    for (int nt = 0; nt < 2; ++nt)
#pragma unroll
        for (int r = 0; r < 4; ++r) {
            const int dd = d0 + lq * 4 + r;
            const long idx = qb + (long)dd * NN + n0 + nt * 16 + ln;
            ug[idx] = qg[idx] - acc2[nt][r];
        }
}

__global__ __launch_bounds__(256)
void colsum_reduce(const float* __restrict__ csp, float* __restrict__ cs, int NT)
{
    int idx = blockIdx.x * 256 + threadIdx.x;   // over B*M
    int b = idx / MM, m = idx - b * MM;
    const float* p = csp + (long)b * NT * MM + m;
    float s = 0.f;
    for (int i = 0; i < NT; ++i) s += p[(long)i * MM];
    cs[idx] = s;
}

__global__ __launch_bounds__(256)
void vscale_cvt(const float* __restrict__ v, const float* __restrict__ cs,
                ushort* __restrict__ vb)
{
    long i4 = (long)blockIdx.x * 256 + threadIdx.x;
    long flat = i4 * 4;                          // index into [B][64][M]
    int b = (int)(flat / (64L * MM));
    int m = (int)(flat % MM);
    float4 vv = *reinterpret_cast<const float4*>(v + flat);
    float4 cv = *reinterpret_cast<const float4*>(cs + (long)b * MM + m);
    ushort4 o;
    o.x = f2bf(vv.x / (1e-9f + cv.x));
    o.y = f2bf(vv.y / (1e-9f + cv.y));
    o.z = f2bf(vv.z / (1e-9f + cv.z));
    o.w = f2bf(vv.w / (1e-9f + cv.w));
    *reinterpret_cast<ushort4*>(vb + flat) = o;
}

// ---------------------------------------------------------------------------
// Final GN4 + relu + transpose (unchanged)
// ---------------------------------------------------------------------------
__global__ __launch_bounds__(256)
void gn_out_transpose(const float* __restrict__ s2,
                      const float* __restrict__ w, const float* __restrict__ bb,
                      const float* __restrict__ stats,
                      float* __restrict__ out)
{
    __shared__ float ls[128 * 65];
    const int t = threadIdx.x;
    const int b = blockIdx.y;
    const int n0 = blockIdx.x * 64;
#pragma unroll
    for (int i = 0; i < 8; ++i) {
        int f4 = i * 256 + t;
        int o = f4 >> 4, c4 = f4 & 15;
        float4 vv = *reinterpret_cast<const float4*>(
            s2 + (long)b * 128 * NN + (long)o * NN + n0 + c4 * 4);
        int sidx = (b * 4 + (o >> 5)) * 2;
        float mu = stats[sidx], rsig = stats[sidx + 1];
        float sc = rsig * w[o], sh = bb[o] - mu * sc;
        ls[o * 65 + c4 * 4 + 0] = fmaxf(vv.x * sc + sh, 0.f);
        ls[o * 65 + c4 * 4 + 1] = fmaxf(vv.y * sc + sh, 0.f);
        ls[o * 65 + c4 * 4 + 2] = fmaxf(vv.z * sc + sh, 0.f);
        ls[o * 65 + c4 * 4 + 3] = fmaxf(vv.w * sc + sh, 0.f);
    }
    __syncthreads();
#pragma unroll
    for (int i = 0; i < 8; ++i) {
        int f4 = i * 256 + t;
        int nn = f4 >> 5, o4 = f4 & 31;
        float4 ov;
        ov.x = ls[(o4 * 4 + 0) * 65 + nn];
        ov.y = ls[(o4 * 4 + 1) * 65 + nn];
        ov.z = ls[(o4 * 4 + 2) * 65 + nn];
        ov.w = ls[(o4 * 4 + 3) * 65 + nn];
        *reinterpret_cast<float4*>(out + (long)b * NN * 128 + (long)(n0 + nn) * 128 + o4 * 4) = ov;
    }
}

} // namespace

extern "C" void kernel_launch(void* const* d_in, const int* in_sizes, int n_in,
                              void* d_out, int out_size, void* d_ws, size_t ws_size,
                              hipStream_t stream)
{
    (void)in_sizes; (void)n_in; (void)out_size; (void)ws_size;

    const float* x         = (const float*)d_in[0];
    const float* x_global  = (const float*)d_in[1];
    const float* xyz       = (const float*)d_in[2];
    const float* xyz_g     = (const float*)d_in[3];
    const float* conv1_w   = (const float*)d_in[4];
    const float* gn1_w     = (const float*)d_in[5];
    const float* gn1_b     = (const float*)d_in[6];
    const float* conv2_w   = (const float*)d_in[7];
    const float* gn2_w     = (const float*)d_in[8];
    const float* gn2_b     = (const float*)d_in[9];
    const float* sa_qk_w   = (const float*)d_in[10];
    const float* sa_v_w    = (const float*)d_in[11];
    const float* sa_v_b    = (const float*)d_in[12];
    const float* sa_t_w    = (const float*)d_in[13];
    const float* sa_t_b    = (const float*)d_in[14];
    const float* sa_gn_w   = (const float*)d_in[15];
    const float* sa_gn_b   = (const float*)d_in[16];
    const float* sa_pos_w  = (const float*)d_in[17];
    const float* sa_posG_w = (const float*)d_in[18];
    const float* fuse_w    = (const float*)d_in[19];
    const float* fuse_gn_w = (const float*)d_in[20];
    const float* fuse_gn_b = (const float*)d_in[21];
    const float* convs1_w  = (const float*)d_in[22];
    const float* convs1_b  = (const float*)d_in[23];
    const float* gns1_w    = (const float*)d_in[24];
    const float* gns1_b    = (const float*)d_in[25];
    const float* convs2_w  = (const float*)d_in[26];
    const float* convs2_b  = (const float*)d_in[27];
    const float* gns2_w    = (const float*)d_in[28];
    const float* gns2_b    = (const float*)d_in[29];

    // ---- workspace layout; identical to round 12 (proven) ----
    constexpr long SZ_BN  = (long)BB * 64 * NN;
    constexpr long SZ_BM  = (long)BB * 64 * MM;
    constexpr long SZ_CSP = (long)BB * (NN / 16) * MM;

    float* ws = (float*)d_ws;
    long o = 0;
    float* p_h   = ws + o; o += SZ_BN;
    float* p_hg  = ws + o; o += SZ_BM;
    float* p_q   = ws + o; o += SZ_BN;
    float* p_k   = ws + o; o += SZ_BM;
    float* p_v   = ws + o; o += SZ_BM;
    float* p_u   = ws + o; o += SZ_BN;
    float* p_csp = ws + o; o += SZ_CSP;
    float* p_cs  = ws + o; o += (long)BB * MM;
    float* p_xc  = ws + o; o += (long)BB * 256 * NN;
    float* p_xf  = ws + o; o += (long)BB * 128 * NN;
    float* p_st  = ws + o; o += 4096;
    float* p_rmx = ws + o; o += (long)BB * NN;
    float* p_rin = ws + o; o += (long)BB * NN;
    float* p_s1  = ws;
    float* p_s2  = p_xf;
    ushort* p_qt = (ushort*)p_xf;
    ushort* p_kt = (ushort*)(p_xf + 2097152);
    ushort* p_vb = (ushort*)(p_xf + 2097152 + 524288);

    // h = relu(GN16(conv1(x)))   (C=6 -> old kernel)
    conv_gemm<<<dim3(NN / 128, 1, BB), 256, 0, stream>>>(
        x, 6, 6L * NN, conv1_w, nullptr, 0, 0, nullptr, nullptr, p_h, 64L * NN, NN);
    gn_stats<<<BB * 16, 256, 0, stream>>>(p_h, 64L * NN, 4, NN, 16, p_st);
    gn_apply<<<2048, 256, 0, stream>>>(p_h, 64L * NN, p_h, 64L * NN, nullptr, 0,
                                       gn1_w, gn1_b, p_st, 64, 4, NN, 1);
    // hg = relu(GN16(conv2(x_global)))   (C=32 -> MFMA)
    conv_mfma<<<dim3(MM / 128, 1, BB), 256, 0, stream>>>(
        x_global, 32, 32L * MM, conv2_w, nullptr, 0, nullptr, nullptr, p_hg, 64L * MM, MM);
    gn_stats<<<BB * 16, 256, 0, stream>>>(p_hg, 64L * MM, 4, MM, 16, p_st);
    gn_apply<<<2048, 256, 0, stream>>>(p_hg, 64L * MM, p_hg, 64L * MM, nullptr, 0,
                                       gn2_w, gn2_b, p_st, 64, 4, MM, 1);

    const float* cur = p_h;
    long cur_bs = 64L * NN;
    for (int i = 0; i < 4; ++i) {
        // q = qk_w*cur + pos_w*xyz
        conv_mfma<<<dim3(NN / 128, 1, BB), 256, 0, stream>>>(
            cur, 64, cur_bs, sa_qk_w + i * 4096,
            xyz, 3L * NN, sa_pos_w + i * 192, nullptr, p_q, 64L * NN, NN);
        tcvt<<<dim3(NN / 64, BB), 256, 0, stream>>>(p_q, p_qt, NN);
        // k = qk_w*hg + posG_w*xyz_g
        conv_mfma<<<dim3(MM / 128, 1, BB), 256, 0, stream>>>(
            p_hg, 64, 64L * MM, sa_qk_w + i * 4096,
            xyz_g, 3L * MM, sa_posG_w + i * 192, nullptr, p_k, 64L * MM, MM);
        tcvt<<<dim3(MM / 64, BB), 256, 0, stream>>>(p_k, p_kt, MM);
        // v = v_w*hg + posG_w*xyz_g + v_b
        conv_mfma<<<dim3(MM / 128, 1, BB), 256, 0, stream>>>(
            p_hg, 64, 64L * MM, sa_v_w + i * 4096,
            xyz_g, 3L * MM, sa_posG_w + i * 192, sa_v_b + i * 64, p_v, 64L * MM, MM);
        // phase 0: MFMA softmax stats + column partials
        attn_stats_mfma<<<dim3(NN / 16, BB), 256, 0, stream>>>(p_qt, p_kt, p_rmx, p_rin, p_csp);
        colsum_reduce<<<BB * MM / 256, 256, 0, stream>>>(p_csp, p_cs, NN / 16);
        vscale_cvt<<<BB * 64 * MM / 1024, 256, 0, stream>>>(p_v, p_cs, p_vb);
        // phase 1: u = q - P*v'  (32-row blocks, chunked QK^T->PV)
        attn_pv_mfma<<<dim3(NN / 32, BB), 256, 0, stream>>>(
            p_qt, p_kt, p_vb, p_rmx, p_rin, p_q, p_u);
        // t = t_w*u + t_b
        conv_mfma<<<dim3(NN / 128, 1, BB), 256, 0, stream>>>(
            p_u, 64, 64L * NN, sa_t_w + i * 4096,
            nullptr, 0, nullptr, sa_t_b + i * 64, p_h, 64L * NN, NN);
        // out_i = q + relu(GN4(t))  -> xc slice i
        gn_stats<<<BB * 4, 256, 0, stream>>>(p_h, 64L * NN, 16, NN, 4, p_st);
        gn_apply<<<2048, 256, 0, stream>>>(p_h, 64L * NN,
                                           p_xc + (long)i * 64 * NN, 256L * NN,
                                           p_q, 64L * NN,
                                           sa_gn_w + i * 64, sa_gn_b + i * 64, p_st,
                                           64, 16, NN, 1);
        cur = p_xc + (long)i * 64 * NN;
        cur_bs = 256L * NN;
    }

    // xf = leaky(GN16(fuse_w * xc))
    conv_mfma<<<dim3(NN / 128, 2, BB), 256, 0, stream>>>(
        p_xc, 256, 256L * NN, fuse_w, nullptr, 0, nullptr, nullptr, p_xf, 128L * NN, NN);
    gn_stats<<<BB * 16, 256, 0, stream>>>(p_xf, 128L * NN, 8, NN, 16, p_st);
    gn_apply<<<2048, 256, 0, stream>>>(p_xf, 128L * NN, p_xf, 128L * NN, nullptr, 0,
                                       fuse_gn_w, fuse_gn_b, p_st, 128, 8, NN, 2);
    // s1 = relu(GN8(convs1_w * xf + b))
    conv_mfma<<<dim3(NN / 128, 8, BB), 256, 0, stream>>>(
        p_xf, 128, 128L * NN, convs1_w, nullptr, 0, nullptr, convs1_b, p_s1, 512L * NN, NN);
    gn_stats<<<BB * 8, 256, 0, stream>>>(p_s1, 512L * NN, 64, NN, 8, p_st);
    gn_apply<<<2048, 256, 0, stream>>>(p_s1, 512L * NN, p_s1, 512L * NN, nullptr, 0,
                                       gns1_w, gns1_b, p_st, 512, 64, NN, 1);
    // s2 = GN4(convs2_w * s1 + b), relu fused into transpose
    conv_mfma<<<dim3(NN / 128, 2, BB), 256, 0, stream>>>(
        p_s1, 512, 512L * NN, convs2_w, nullptr, 0, nullptr, convs2_b, p_s2, 128L * NN, NN);
    gn_stats<<<BB * 4, 256, 0, stream>>>(p_s2, 128L * NN, 32, NN, 4, p_st);
    gn_out_transpose<<<dim3(NN / 64, BB), 256, 0, stream>>>(
        p_s2, gns2_w, gns2_b, p_st, (float*)d_out);
}